// Round 1
// baseline (3843.343 us; speedup 1.0000x reference)
//
#include <hip/hip_runtime.h>
#include <hip/hip_bf16.h>

// Problem dims (fixed)
#define BB 64      // batch
#define PP 196     // patches
#define ENCD 512   // encoder dim
#define ED 1024    // embed dim
#define HD 1024    // hidden
#define AD 512     // attention dim
#define VD 20000   // vocab
#define TT 24      // timesteps = lengths-1

// ---------------- mean over patches ----------------
__global__ __launch_bounds__(512) void mean_kernel(const float* __restrict__ enc,
                                                   float* __restrict__ mf) {
    int b = blockIdx.x; int e = threadIdx.x;   // 512 threads
    const float* base = enc + (size_t)b * PP * ENCD + e;
    float s = 0.f;
    #pragma unroll 4
    for (int p = 0; p < PP; ++p) s += base[(size_t)p * ENCD];
    mf[b * ENCD + e] = s * (1.f / PP);
}

// ---------------- h0/c0 init: mf @ W + b ----------------
__global__ __launch_bounds__(256) void init_hc_kernel(
    const float* __restrict__ mf,
    const float* __restrict__ Wh, const float* __restrict__ bh,
    const float* __restrict__ Wc, const float* __restrict__ bc,
    float* __restrict__ h0, float* __restrict__ c0) {
    int b = blockIdx.x;
    const float* W    = blockIdx.y ? Wc : Wh;
    const float* bias = blockIdx.y ? bc : bh;
    float* out        = blockIdx.y ? c0 : h0;
    __shared__ float smf[ENCD];
    for (int i = threadIdx.x; i < ENCD; i += 256) smf[i] = mf[b * ENCD + i];
    __syncthreads();
    #pragma unroll
    for (int jj = 0; jj < 4; ++jj) {
        int j = threadIdx.x + jj * 256;
        float acc = bias[j];
        for (int k = 0; k < ENCD; ++k) acc += smf[k] * W[(size_t)k * HD + j];
        out[b * HD + j] = acc;
    }
}

// ---------------- embedding gather ----------------
__global__ __launch_bounds__(256) void embed_kernel(const int* __restrict__ captions,
                                                    const float* __restrict__ table,
                                                    float* __restrict__ emb) {
    int t = blockIdx.x, b = blockIdx.y;
    int tok = captions[b * 25 + t];
    const float4* src = (const float4*)(table + (size_t)tok * ED);
    float4* dst = (float4*)(emb + ((size_t)t * BB + b) * ED);
    dst[threadIdx.x] = src[threadIdx.x];   // 256 * float4 = 1024 floats
}

// ---------------- generic fp32 GEMM: C[row(m)] = A[m]@B + bias ----------------
// 128x64 tile, 256 threads, micro 8x4. remap=1 maps A-row r=(t*64+b) -> out row b*24+t.
__global__ __launch_bounds__(256) void gemm128_kernel(
    const float* __restrict__ Ap, const float* __restrict__ Bp,
    const float* __restrict__ bias, float* __restrict__ Cp,
    int M, int N, int K, int remap) {
    __shared__ __align__(16) float As[32][132];   // As[k][m], stride 132 keeps rows 16B-aligned
    __shared__ __align__(16) float Bs[32][64];
    int m0 = blockIdx.y * 128;
    int n0 = blockIdx.x * 64;
    int tid = threadIdx.x;
    int tm = tid & 15, tn = tid >> 4;
    float acc[8][4] = {};
    for (int k0 = 0; k0 < K; k0 += 32) {
        #pragma unroll
        for (int i = 0; i < 4; ++i) {
            int idx = tid + i * 256; int sm = idx >> 3; int sk = (idx & 7) * 4;
            float4 v = *(const float4*)(Ap + (size_t)(m0 + sm) * K + k0 + sk);
            As[sk][sm] = v.x; As[sk + 1][sm] = v.y; As[sk + 2][sm] = v.z; As[sk + 3][sm] = v.w;
        }
        #pragma unroll
        for (int i = 0; i < 2; ++i) {
            int idx = tid + i * 256; int k = idx >> 4; int n4 = (idx & 15) * 4;
            int n = n0 + n4; if (n > N - 4) n = N - 4;   // clamp (tail tile)
            float4 v = *(const float4*)(Bp + (size_t)(k0 + k) * N + n);
            *(float4*)&Bs[k][n4] = v;
        }
        __syncthreads();
        #pragma unroll 8
        for (int k = 0; k < 32; ++k) {
            float a[8], bb[4];
            *(float4*)&a[0] = *(const float4*)&As[k][tm * 8];
            *(float4*)&a[4] = *(const float4*)&As[k][tm * 8 + 4];
            *(float4*)&bb[0] = *(const float4*)&Bs[k][tn * 4];
            #pragma unroll
            for (int i = 0; i < 8; ++i)
                #pragma unroll
                for (int j = 0; j < 4; ++j) acc[i][j] += a[i] * bb[j];
        }
        __syncthreads();
    }
    #pragma unroll
    for (int i = 0; i < 8; ++i) {
        int r = m0 + tm * 8 + i;
        int row = remap ? ((r & 63) * TT + (r >> 6)) : r;
        int n = n0 + tn * 4;
        float* dst = Cp + (size_t)row * N + n;
        #pragma unroll
        for (int j = 0; j < 4; ++j)
            if (n + j < N) dst[j] = acc[i][j] + bias[n + j];
    }
}

// ---------------- per-step: att_dec & gate pre-activation (K-split 4) ----------------
// Combined N=1024: n<512 -> h@W_dec col n ; n>=512 -> h@W_fbeta col n-512. No bias here.
__global__ __launch_bounds__(256) void attdec_gate_kernel(
    const float* __restrict__ h, const float* __restrict__ Wd,
    const float* __restrict__ Wf, float* __restrict__ outp /*[4][64][1024]*/) {
    int n0 = blockIdx.x * 16;   // 0..1008
    int ks = blockIdx.y;        // 0..3
    int tid = threadIdx.x;
    int m = tid & 63, ng = tid >> 6;
    const float* W = (n0 < AD) ? (Wd + n0) : (Wf + n0 - AD);
    __shared__ __align__(16) float hs[32][65];
    __shared__ __align__(16) float wsh[32][16];
    float acc[4] = {0, 0, 0, 0};
    for (int kc = 0; kc < 256; kc += 32) {
        int k0 = ks * 256 + kc;
        #pragma unroll
        for (int i = 0; i < 2; ++i) {
            int idx = tid + i * 256; int sm = idx >> 3; int sk = (idx & 7) * 4;
            float4 v = *(const float4*)(h + (size_t)sm * HD + k0 + sk);
            hs[sk][sm] = v.x; hs[sk + 1][sm] = v.y; hs[sk + 2][sm] = v.z; hs[sk + 3][sm] = v.w;
        }
        if (tid < 128) {
            int k = tid >> 2; int n4 = (tid & 3) * 4;
            *(float4*)&wsh[k][n4] = *(const float4*)(W + (size_t)(k0 + k) * AD + n4);
        }
        __syncthreads();
        #pragma unroll
        for (int k = 0; k < 32; ++k) {
            float a = hs[k][m];
            float4 wv = *(const float4*)&wsh[k][ng * 4];
            acc[0] += a * wv.x; acc[1] += a * wv.y; acc[2] += a * wv.z; acc[3] += a * wv.w;
        }
        __syncthreads();
    }
    float* o = outp + ((size_t)ks * BB + m) * 1024 + n0 + ng * 4;
    o[0] = acc[0]; o[1] = acc[1]; o[2] = acc[2]; o[3] = acc[3];
}

// ---------------- per-step: energy + softmax -> alphas ----------------
__global__ __launch_bounds__(256) void energy_softmax_kernel(
    const float* __restrict__ att_enc, const float* __restrict__ adg,
    const float* __restrict__ b_dec, const float* __restrict__ Wfull,
    float* __restrict__ alpha, int t) {
    int b = blockIdx.x; int tid = threadIdx.x;
    __shared__ float sdec[AD], sw[AD];
    for (int i = tid; i < AD; i += 256) {
        float s = b_dec[i];
        s += adg[((size_t)0 * BB + b) * 1024 + i];
        s += adg[((size_t)1 * BB + b) * 1024 + i];
        s += adg[((size_t)2 * BB + b) * 1024 + i];
        s += adg[((size_t)3 * BB + b) * 1024 + i];
        sdec[i] = s;
        sw[i] = Wfull[i];
    }
    __syncthreads();
    float myE = -1e30f;
    if (tid < PP) {
        const float* row = att_enc + ((size_t)b * PP + tid) * AD;
        float s = 0.f;
        #pragma unroll 4
        for (int a0 = 0; a0 < AD; a0 += 4) {
            float4 v = *(const float4*)(row + a0);
            s += fmaxf(v.x + sdec[a0 + 0], 0.f) * sw[a0 + 0];
            s += fmaxf(v.y + sdec[a0 + 1], 0.f) * sw[a0 + 1];
            s += fmaxf(v.z + sdec[a0 + 2], 0.f) * sw[a0 + 2];
            s += fmaxf(v.w + sdec[a0 + 3], 0.f) * sw[a0 + 3];
        }
        myE = s;
    }
    __shared__ float red[256];
    red[tid] = myE; __syncthreads();
    for (int s = 128; s > 0; s >>= 1) {
        if (tid < s) red[tid] = fmaxf(red[tid], red[tid + s]);
        __syncthreads();
    }
    float mx = red[0]; __syncthreads();
    float ex = (tid < PP) ? __expf(myE - mx) : 0.f;
    red[tid] = ex; __syncthreads();
    for (int s = 128; s > 0; s >>= 1) {
        if (tid < s) red[tid] += red[tid + s];
        __syncthreads();
    }
    float inv = 1.f / red[0];
    if (tid < PP) alpha[((size_t)b * TT + t) * PP + tid] = ex * inv;
}

// ---------------- per-step: context + gated x2 ----------------
__global__ __launch_bounds__(256) void context_x2_kernel(
    const float* __restrict__ enc, const float* __restrict__ alpha,
    const float* __restrict__ adg, const float* __restrict__ b_fbeta,
    float* __restrict__ x2, int t) {
    int b = blockIdx.x;
    int e = blockIdx.y * 256 + threadIdx.x;
    __shared__ float sal[PP];
    if (threadIdx.x < PP) sal[threadIdx.x] = alpha[((size_t)b * TT + t) * PP + threadIdx.x];
    __syncthreads();
    const float* base = enc + (size_t)b * PP * ENCD + e;
    float s = 0.f;
    #pragma unroll 4
    for (int p = 0; p < PP; ++p) s += sal[p] * base[(size_t)p * ENCD];
    float gpre = b_fbeta[e];
    gpre += adg[((size_t)0 * BB + b) * 1024 + AD + e];
    gpre += adg[((size_t)1 * BB + b) * 1024 + AD + e];
    gpre += adg[((size_t)2 * BB + b) * 1024 + AD + e];
    gpre += adg[((size_t)3 * BB + b) * 1024 + AD + e];
    float gate = 1.f / (1.f + __expf(-gpre));
    x2[b * ENCD + e] = gate * s;
}

// ---------------- per-step: gates GEMM (K-split 2), K = 1024(emb)+512(x2)+1024(h) ----------------
__global__ __launch_bounds__(256) void gates_kernel(
    const float* __restrict__ embt, const float* __restrict__ x2,
    const float* __restrict__ h, const float* __restrict__ Wih,
    const float* __restrict__ Whh, float* __restrict__ gp /*[2][64][4096]*/) {
    int n0 = blockIdx.x * 16;
    int ks = blockIdx.y;
    int tid = threadIdx.x;
    int m = tid & 63, ng = tid >> 6;
    __shared__ __align__(16) float hs[32][65];
    __shared__ __align__(16) float wsh[32][16];
    float acc[4] = {0, 0, 0, 0};
    for (int k0 = ks * 1280; k0 < (ks + 1) * 1280; k0 += 32) {
        #pragma unroll
        for (int i = 0; i < 2; ++i) {
            int idx = tid + i * 256; int sm = idx >> 3; int sk = (idx & 7) * 4;
            const float* sp;
            if (k0 < 1024)      sp = embt + (size_t)sm * ED + k0 + sk;
            else if (k0 < 1536) sp = x2 + (size_t)sm * ENCD + (k0 - 1024) + sk;
            else                sp = h + (size_t)sm * HD + (k0 - 1536) + sk;
            float4 v = *(const float4*)sp;
            hs[sk][sm] = v.x; hs[sk + 1][sm] = v.y; hs[sk + 2][sm] = v.z; hs[sk + 3][sm] = v.w;
        }
        if (tid < 128) {
            int k = tid >> 2; int n4 = (tid & 3) * 4;
            const float* wp = (k0 < 1536) ? (Wih + (size_t)(k0 + k) * 4096 + n0 + n4)
                                          : (Whh + (size_t)(k0 - 1536 + k) * 4096 + n0 + n4);
            *(float4*)&wsh[k][n4] = *(const float4*)wp;
        }
        __syncthreads();
        #pragma unroll
        for (int k = 0; k < 32; ++k) {
            float a = hs[k][m];
            float4 wv = *(const float4*)&wsh[k][ng * 4];
            acc[0] += a * wv.x; acc[1] += a * wv.y; acc[2] += a * wv.z; acc[3] += a * wv.w;
        }
        __syncthreads();
    }
    float* o = gp + ((size_t)ks * BB + m) * 4096 + n0 + ng * 4;
    o[0] = acc[0]; o[1] = acc[1]; o[2] = acc[2]; o[3] = acc[3];
}

// ---------------- per-step: LSTM pointwise ----------------
__global__ __launch_bounds__(256) void lstm_kernel(
    const float* __restrict__ gp, const float* __restrict__ b_ih,
    const float* __restrict__ b_hh, float* __restrict__ c,
    float* __restrict__ h_new) {
    int b = blockIdx.x; int tid = threadIdx.x;
    const float* g0 = gp + (size_t)b * 4096;
    const float* g1 = gp + (size_t)(BB + b) * 4096;
    #pragma unroll
    for (int jj = 0; jj < 4; ++jj) {
        int j = tid + jj * 256;
        float gi = g0[j] + g1[j] + b_ih[j] + b_hh[j];
        float gf = g0[1024 + j] + g1[1024 + j] + b_ih[1024 + j] + b_hh[1024 + j];
        float gg = g0[2048 + j] + g1[2048 + j] + b_ih[2048 + j] + b_hh[2048 + j];
        float go = g0[3072 + j] + g1[3072 + j] + b_ih[3072 + j] + b_hh[3072 + j];
        float si = 1.f / (1.f + __expf(-gi));
        float sf = 1.f / (1.f + __expf(-gf));
        float so = 1.f / (1.f + __expf(-go));
        float cn = sf * c[b * HD + j] + si * tanhf(gg);
        c[b * HD + j] = cn;
        h_new[b * HD + j] = so * tanhf(cn);
    }
}

extern "C" void kernel_launch(void* const* d_in, const int* in_sizes, int n_in,
                              void* d_out, int out_size, void* d_ws, size_t ws_size,
                              hipStream_t stream) {
    const float* enc      = (const float*)d_in[0];
    const int*   captions = (const int*)d_in[1];
    // d_in[2] = lengths (25) -> T = 24, compile-time
    const float* W_enc    = (const float*)d_in[3];
    const float* b_enc    = (const float*)d_in[4];
    const float* W_dec    = (const float*)d_in[5];
    const float* b_dec    = (const float*)d_in[6];
    const float* W_full   = (const float*)d_in[7];
    // d_in[8] = b_full_att: softmax-invariant, skipped
    const float* table    = (const float*)d_in[9];
    const float* W_ih     = (const float*)d_in[10];
    const float* b_ih     = (const float*)d_in[11];
    const float* W_hh     = (const float*)d_in[12];
    const float* b_hh     = (const float*)d_in[13];
    const float* W_init_h = (const float*)d_in[14];
    const float* b_init_h = (const float*)d_in[15];
    const float* W_init_c = (const float*)d_in[16];
    const float* b_init_c = (const float*)d_in[17];
    const float* W_fbeta  = (const float*)d_in[18];
    const float* b_fbeta  = (const float*)d_in[19];
    const float* W_fc     = (const float*)d_in[20];
    const float* b_fc     = (const float*)d_in[21];

    float* preds  = (float*)d_out;                       // [64][24][20000]
    float* alphas = (float*)d_out + (size_t)BB * TT * VD; // [64][24][196]

    // workspace layout (floats)
    float* ws      = (float*)d_ws;
    float* att_enc = ws;                        // 12544*512   = 6422528
    float* h_buf   = att_enc + 6422528;         // 25*64*1024  = 1638400
    float* c_buf   = h_buf + 1638400;           // 64*1024     = 65536
    float* emb     = c_buf + 65536;             // 24*64*1024  = 1572864
    float* adg     = emb + 1572864;             // 4*64*1024   = 262144
    float* x2      = adg + 262144;              // 64*512      = 32768
    float* gp      = x2 + 32768;                // 2*64*4096   = 524288
    float* mf      = gp + 524288;               // 64*512      = 32768
    // total ~10.55M floats ~ 42.2 MB

    mean_kernel<<<BB, 512, 0, stream>>>(enc, mf);
    init_hc_kernel<<<dim3(BB, 2), 256, 0, stream>>>(mf, W_init_h, b_init_h, W_init_c, b_init_c,
                                                    h_buf, c_buf);
    embed_kernel<<<dim3(TT, BB), 256, 0, stream>>>(captions, table, emb);
    // att_enc = enc @ W_enc + b_enc : M=12544 N=512 K=512
    gemm128_kernel<<<dim3(8, 98), 256, 0, stream>>>(enc, W_enc, b_enc, att_enc, 12544, 512, 512, 0);

    for (int t = 0; t < TT; ++t) {
        const float* h = h_buf + (size_t)t * BB * HD;
        attdec_gate_kernel<<<dim3(64, 4), 256, 0, stream>>>(h, W_dec, W_fbeta, adg);
        energy_softmax_kernel<<<BB, 256, 0, stream>>>(att_enc, adg, b_dec, W_full, alphas, t);
        context_x2_kernel<<<dim3(BB, 2), 256, 0, stream>>>(enc, alphas, adg, b_fbeta, x2, t);
        gates_kernel<<<dim3(256, 2), 256, 0, stream>>>(emb + (size_t)t * BB * ED, x2, h, W_ih, W_hh, gp);
        lstm_kernel<<<BB, 256, 0, stream>>>(gp, b_ih, b_hh, c_buf, h_buf + (size_t)(t + 1) * BB * HD);
    }

    // preds = h_all @ W_fc + b_fc : M=1536 N=20000 K=1024, rows remapped (t,b)->(b,t)
    gemm128_kernel<<<dim3(313, 12), 256, 0, stream>>>(h_buf + (size_t)BB * HD, W_fc, b_fc, preds,
                                                      TT * BB, VD, HD, 1);
}

// Round 3
// 2025.797 us; speedup vs baseline: 1.8972x; 1.8972x over previous
//
#include <hip/hip_runtime.h>
#include <hip/hip_bf16.h>

// Problem dims (fixed)
#define BB 64      // batch
#define PP 196     // patches
#define ENCD 512   // encoder dim
#define ED 1024    // embed dim
#define HD 1024    // hidden
#define AD 512     // attention dim
#define VD 20000   // vocab
#define TT 24      // timesteps = lengths-1
#define VPAD 20096 // vocab padded to 128

typedef __attribute__((ext_vector_type(8))) short short8;
typedef __attribute__((ext_vector_type(4))) short short4v;
typedef __attribute__((ext_vector_type(4))) float f32x4;

// ---- fp32 -> bf16 split (hi + lo), RNE ----
__device__ __forceinline__ unsigned short f2bf(float f) {
    unsigned u = __builtin_bit_cast(unsigned, f);
    u = (u + 0x7FFFu + ((u >> 16) & 1u)) >> 16;
    return (unsigned short)u;
}
__device__ __forceinline__ void split2(float v, unsigned short& h, unsigned short& l) {
    h = f2bf(v);
    float hf = __builtin_bit_cast(float, ((unsigned)h) << 16);
    l = f2bf(v - hf);
}

// ---- weight split: fp32 [K][N] -> chunked bf16 [K/8][Npad][8] hi/lo (zero-pad cols) ----
__global__ __launch_bounds__(256) void split_w_kernel(
    const float* __restrict__ W, unsigned short* __restrict__ oh,
    unsigned short* __restrict__ ol, int N, int Npad, int coff, int Nlaunch) {
    int n = blockIdx.x * 256 + threadIdx.x;
    if (n >= Nlaunch) return;
    int kc = blockIdx.y;
    short8 vh, vl;
    #pragma unroll
    for (int j = 0; j < 8; ++j) {
        float v = (n < N) ? W[(size_t)(kc * 8 + j) * N + n] : 0.f;
        unsigned short h, l; split2(v, h, l);
        vh[j] = (short)h; vl[j] = (short)l;
    }
    size_t o = ((size_t)kc * Npad + coff + n) * 8;
    *(short8*)(oh + o) = vh; *(short8*)(ol + o) = vl;
}

// ---- embedding gather + split -> per-t chunked [128][64][8] ----
__global__ __launch_bounds__(128) void embed_split_kernel(
    const int* __restrict__ captions, const float* __restrict__ table,
    unsigned short* __restrict__ eh, unsigned short* __restrict__ el) {
    int t = blockIdx.x, b = blockIdx.y;
    int kc = threadIdx.x;   // 0..127
    int tok = captions[b * 25 + t];
    const float* row = table + (size_t)tok * ED;
    short8 vh, vl;
    #pragma unroll
    for (int j = 0; j < 8; ++j) {
        unsigned short h, l; split2(row[kc * 8 + j], h, l);
        vh[j] = (short)h; vl[j] = (short)l;
    }
    size_t o = ((size_t)t * 128 * 64 + (size_t)kc * 64 + b) * 8;
    *(short8*)(eh + o) = vh; *(short8*)(el + o) = vl;
}

// ---- mean over patches ----
__global__ __launch_bounds__(512) void mean_kernel(const float* __restrict__ enc,
                                                   float* __restrict__ mf) {
    int b = blockIdx.x; int e = threadIdx.x;
    const float* base = enc + (size_t)b * PP * ENCD + e;
    float s = 0.f;
    #pragma unroll 4
    for (int p = 0; p < PP; ++p) s += base[(size_t)p * ENCD];
    mf[b * ENCD + e] = s * (1.f / PP);
}

// ---- h0/c0 init; h0 goes straight to chunked bf16 split ----
__global__ __launch_bounds__(256) void init_hc_kernel(
    const float* __restrict__ mf,
    const float* __restrict__ Wh, const float* __restrict__ bh,
    const float* __restrict__ Wc, const float* __restrict__ bc,
    unsigned short* __restrict__ hc_h, unsigned short* __restrict__ hc_l,
    float* __restrict__ c0) {
    int b = blockIdx.x;
    int isC = blockIdx.y;
    const float* W    = isC ? Wc : Wh;
    const float* bias = isC ? bc : bh;
    __shared__ float smf[ENCD];
    for (int i = threadIdx.x; i < ENCD; i += 256) smf[i] = mf[b * ENCD + i];
    __syncthreads();
    #pragma unroll
    for (int jj = 0; jj < 4; ++jj) {
        int j = threadIdx.x + jj * 256;
        float acc = bias[j];
        for (int k = 0; k < ENCD; ++k) acc += smf[k] * W[(size_t)k * HD + j];
        if (isC) c0[b * HD + j] = acc;
        else {
            unsigned short h, l; split2(acc, h, l);
            size_t o = ((size_t)(j >> 3) * 64 + b) * 8 + (j & 7);
            hc_h[o] = h; hc_l[o] = l;
        }
    }
}

// ---- big MFMA GEMM, A from fp32 [Mtot][K] row-major (in-kernel split),
//      B pre-split chunked [K/8][Npad][8] hi/lo. 3-pass. tile 128x128, 4 waves, BK=64 ----
__global__ __launch_bounds__(256) void mfma_gemm_bigf(
    const float* __restrict__ Ap,
    const unsigned short* __restrict__ Bh, const unsigned short* __restrict__ Bl,
    const float* __restrict__ bias, float* __restrict__ C,
    int Mtot, int N, int Npad, int K) {
    __shared__ __align__(16) short lds[32768];   // 64 KB
    short* Ahs = lds;          // [8][128(m^kc)][8]
    short* Als = lds + 8192;
    short* Bhs = lds + 16384;  // [8][128][8]
    short* Bls = lds + 24576;
    int tid = threadIdx.x, lane = tid & 63, w = tid >> 6;
    int m0 = blockIdx.y * 128, n0 = blockIdx.x * 128;
    int wr = w >> 1, wc = w & 1;
    f32x4 acc[4][4];
    #pragma unroll
    for (int i = 0; i < 4; ++i)
        #pragma unroll
        for (int j = 0; j < 4; ++j) acc[i][j] = (f32x4){0.f, 0.f, 0.f, 0.f};
    int nsteps = K >> 6;
    for (int s = 0; s < nsteps; ++s) {
        int k0 = s * 64, kc0 = s * 8;
        // A fp32 tile 128m x 64k, coalesced along k
        float4 va[8];
        #pragma unroll
        for (int it = 0; it < 8; ++it) {
            int idx = it * 256 + tid; int m = idx >> 4, k4 = idx & 15;
            va[it] = *(const float4*)(Ap + (size_t)(m0 + m) * K + k0 + k4 * 4);
        }
        // B chunked short8 loads
        short8 rb[2][4];
        #pragma unroll
        for (int it = 0; it < 4; ++it) {
            int g = w * 4 + it; int kcl = g >> 1; int rb0 = (g & 1) * 64;
            size_t gb = ((size_t)(kc0 + kcl) * Npad + n0 + rb0 + lane) * 8;
            rb[0][it] = *(const short8*)(Bh + gb);
            rb[1][it] = *(const short8*)(Bl + gb);
        }
        __syncthreads();   // previous iteration's LDS reads complete
        // A: split + swizzled b64 writes
        #pragma unroll
        for (int it = 0; it < 8; ++it) {
            int idx = it * 256 + tid; int m = idx >> 4, k4 = idx & 15;
            int kc = k4 >> 1, jh = (k4 & 1) * 4;
            float vv[4] = {va[it].x, va[it].y, va[it].z, va[it].w};
            short4v hv, lv;
            #pragma unroll
            for (int q = 0; q < 4; ++q) {
                unsigned short h, l; split2(vv[q], h, l);
                hv[q] = (short)h; lv[q] = (short)l;
            }
            int o = kc * 1024 + ((m ^ kc) << 3) + jh;
            *(short4v*)(Ahs + o) = hv;
            *(short4v*)(Als + o) = lv;
        }
        // B: linear b128 writes
        #pragma unroll
        for (int it = 0; it < 4; ++it) {
            int g = w * 4 + it; int kcl = g >> 1; int rb0 = (g & 1) * 64;
            int o = (kcl * 128 + rb0 + lane) * 8;
            *(short8*)(Bhs + o) = rb[0][it];
            *(short8*)(Bls + o) = rb[1][it];
        }
        __syncthreads();
        #pragma unroll
        for (int ks = 0; ks < 2; ++ks) {
            int kq = ks * 4 + (lane >> 4);
            short8 afh[4], afl[4], bfh[4], bfl[4];
            #pragma unroll
            for (int mi = 0; mi < 4; ++mi) {
                int row = wr * 64 + mi * 16 + (lane & 15);
                int o = kq * 1024 + ((row ^ kq) << 3);
                afh[mi] = *(const short8*)(Ahs + o);
                afl[mi] = *(const short8*)(Als + o);
            }
            #pragma unroll
            for (int ni = 0; ni < 4; ++ni) {
                int o = (kq * 128 + wc * 64 + ni * 16 + (lane & 15)) * 8;
                bfh[ni] = *(const short8*)(Bhs + o);
                bfl[ni] = *(const short8*)(Bls + o);
            }
            #pragma unroll
            for (int mi = 0; mi < 4; ++mi)
                #pragma unroll
                for (int ni = 0; ni < 4; ++ni) {
                    acc[mi][ni] = __builtin_amdgcn_mfma_f32_16x16x32_bf16(afh[mi], bfh[ni], acc[mi][ni], 0, 0, 0);
                    acc[mi][ni] = __builtin_amdgcn_mfma_f32_16x16x32_bf16(afh[mi], bfl[ni], acc[mi][ni], 0, 0, 0);
                    acc[mi][ni] = __builtin_amdgcn_mfma_f32_16x16x32_bf16(afl[mi], bfh[ni], acc[mi][ni], 0, 0, 0);
                }
        }
    }
    #pragma unroll
    for (int mi = 0; mi < 4; ++mi) {
        int r = m0 + wr * 64 + mi * 16 + ((lane >> 4) << 2);
        #pragma unroll
        for (int ni = 0; ni < 4; ++ni) {
            int c = n0 + wc * 64 + ni * 16 + (lane & 15);
            if (c < N) {
                float bv = bias ? bias[c] : 0.f;
                #pragma unroll
                for (int q = 0; q < 4; ++q)
                    C[(size_t)(r + q) * N + c] = acc[mi][ni][q] + bv;
            }
        }
    }
}

// ---- small-M MFMA GEMM: M=64, tile 64x128, BK=64, K-split via blockIdx.y ----
// A from up to 3 chunked segments (kc boundaries c0,c1); B from 2 segments (bc0).
// out layout [nsplit][64][Npad], no bias.
__global__ __launch_bounds__(256) void mfma_gemm_small(
    const unsigned short* __restrict__ A0h, const unsigned short* __restrict__ A0l,
    const unsigned short* __restrict__ A1h, const unsigned short* __restrict__ A1l,
    const unsigned short* __restrict__ A2h, const unsigned short* __restrict__ A2l,
    int c0, int c1,
    const unsigned short* __restrict__ B0h, const unsigned short* __restrict__ B0l,
    const unsigned short* __restrict__ B1h, const unsigned short* __restrict__ B1l,
    int bc0, float* __restrict__ out, int Npad, int steps) {
    __shared__ __align__(16) short lds[24576];   // 48 KB
    short* Ahs = lds;          // [8][64][8]
    short* Als = lds + 4096;
    short* Bhs = lds + 8192;   // [8][128][8]
    short* Bls = lds + 16384;
    int tid = threadIdx.x, lane = tid & 63, w = tid >> 6;
    int n0 = blockIdx.x * 128;
    int kc_base = blockIdx.y * steps * 8;
    out += (size_t)blockIdx.y * 64 * Npad;
    f32x4 acc[4][2];
    #pragma unroll
    for (int i = 0; i < 4; ++i)
        #pragma unroll
        for (int j = 0; j < 2; ++j) acc[i][j] = (f32x4){0.f, 0.f, 0.f, 0.f};
    for (int s = 0; s < steps; ++s) {
        int kc0 = kc_base + s * 8;
        short8 raa[2][2], rbb[2][4];
        #pragma unroll
        for (int it = 0; it < 2; ++it) {
            int kcl = w * 2 + it; int kcg = kc0 + kcl;
            const unsigned short *ph, *pl; size_t off;
            if (kcg < c0)       { ph = A0h; pl = A0l; off = ((size_t)kcg * 64 + lane) * 8; }
            else if (kcg < c1)  { ph = A1h; pl = A1l; off = ((size_t)(kcg - c0) * 64 + lane) * 8; }
            else                { ph = A2h; pl = A2l; off = ((size_t)(kcg - c1) * 64 + lane) * 8; }
            raa[0][it] = *(const short8*)(ph + off);
            raa[1][it] = *(const short8*)(pl + off);
        }
        #pragma unroll
        for (int it = 0; it < 4; ++it) {
            int g = w * 4 + it; int kcl = g >> 1; int cb = (g & 1) * 64; int kcg = kc0 + kcl;
            const unsigned short *ph, *pl; size_t off;
            if (kcg < bc0) { ph = B0h; pl = B0l; off = ((size_t)kcg * Npad + n0 + cb + lane) * 8; }
            else           { ph = B1h; pl = B1l; off = ((size_t)(kcg - bc0) * Npad + n0 + cb + lane) * 8; }
            rbb[0][it] = *(const short8*)(ph + off);
            rbb[1][it] = *(const short8*)(pl + off);
        }
        __syncthreads();
        #pragma unroll
        for (int it = 0; it < 2; ++it) {
            int kcl = w * 2 + it; int o = (kcl * 64 + lane) * 8;
            *(short8*)(Ahs + o) = raa[0][it];
            *(short8*)(Als + o) = raa[1][it];
        }
        #pragma unroll
        for (int it = 0; it < 4; ++it) {
            int g = w * 4 + it; int kcl = g >> 1; int cb = (g & 1) * 64;
            int o = (kcl * 128 + cb + lane) * 8;
            *(short8*)(Bhs + o) = rbb[0][it];
            *(short8*)(Bls + o) = rbb[1][it];
        }
        __syncthreads();
        #pragma unroll
        for (int ks = 0; ks < 2; ++ks) {
            int kq = ks * 4 + (lane >> 4);
            short8 afh[4], afl[4], bfh[2], bfl[2];
            #pragma unroll
            for (int mi = 0; mi < 4; ++mi) {
                int o = (kq * 64 + mi * 16 + (lane & 15)) * 8;
                afh[mi] = *(const short8*)(Ahs + o);
                afl[mi] = *(const short8*)(Als + o);
            }
            #pragma unroll
            for (int ni = 0; ni < 2; ++ni) {
                int o = (kq * 128 + w * 32 + ni * 16 + (lane & 15)) * 8;
                bfh[ni] = *(const short8*)(Bhs + o);
                bfl[ni] = *(const short8*)(Bls + o);
            }
            #pragma unroll
            for (int mi = 0; mi < 4; ++mi)
                #pragma unroll
                for (int ni = 0; ni < 2; ++ni) {
                    acc[mi][ni] = __builtin_amdgcn_mfma_f32_16x16x32_bf16(afh[mi], bfh[ni], acc[mi][ni], 0, 0, 0);
                    acc[mi][ni] = __builtin_amdgcn_mfma_f32_16x16x32_bf16(afh[mi], bfl[ni], acc[mi][ni], 0, 0, 0);
                    acc[mi][ni] = __builtin_amdgcn_mfma_f32_16x16x32_bf16(afl[mi], bfh[ni], acc[mi][ni], 0, 0, 0);
                }
        }
        __syncthreads();
    }
    #pragma unroll
    for (int mi = 0; mi < 4; ++mi) {
        int r = mi * 16 + ((lane >> 4) << 2);
        #pragma unroll
        for (int ni = 0; ni < 2; ++ni) {
            int c = n0 + w * 32 + ni * 16 + (lane & 15);
            #pragma unroll
            for (int q = 0; q < 4; ++q)
                out[(size_t)(r + q) * Npad + c] = acc[mi][ni][q];
        }
    }
}

// ---- energy + softmax -> alphas ----
__global__ __launch_bounds__(256) void energy_softmax_kernel(
    const float* __restrict__ att_enc, const float* __restrict__ adg,
    const float* __restrict__ b_dec, const float* __restrict__ Wfull,
    float* __restrict__ alpha, int t) {
    int b = blockIdx.x; int tid = threadIdx.x;
    __shared__ float sdec[AD], sw[AD];
    for (int i = tid; i < AD; i += 256) {
        float s = b_dec[i];
        s += adg[((size_t)0 * BB + b) * 1024 + i];
        s += adg[((size_t)1 * BB + b) * 1024 + i];
        s += adg[((size_t)2 * BB + b) * 1024 + i];
        s += adg[((size_t)3 * BB + b) * 1024 + i];
        sdec[i] = s;
        sw[i] = Wfull[i];
    }
    __syncthreads();
    float myE = -1e30f;
    if (tid < PP) {
        const float* row = att_enc + ((size_t)b * PP + tid) * AD;
        float s = 0.f;
        #pragma unroll 4
        for (int a0 = 0; a0 < AD; a0 += 4) {
            float4 v = *(const float4*)(row + a0);
            s += fmaxf(v.x + sdec[a0 + 0], 0.f) * sw[a0 + 0];
            s += fmaxf(v.y + sdec[a0 + 1], 0.f) * sw[a0 + 1];
            s += fmaxf(v.z + sdec[a0 + 2], 0.f) * sw[a0 + 2];
            s += fmaxf(v.w + sdec[a0 + 3], 0.f) * sw[a0 + 3];
        }
        myE = s;
    }
    __shared__ float red[256];
    red[tid] = myE; __syncthreads();
    for (int s = 128; s > 0; s >>= 1) {
        if (tid < s) red[tid] = fmaxf(red[tid], red[tid + s]);
        __syncthreads();
    }
    float mx = red[0]; __syncthreads();
    float ex = (tid < PP) ? __expf(myE - mx) : 0.f;
    red[tid] = ex; __syncthreads();
    for (int s = 128; s > 0; s >>= 1) {
        if (tid < s) red[tid] += red[tid + s];
        __syncthreads();
    }
    float inv = 1.f / red[0];
    if (tid < PP) alpha[((size_t)b * TT + t) * PP + tid] = ex * inv;
}

// ---- context + gate -> x2 chunked split ----
__global__ __launch_bounds__(256) void context_x2_kernel(
    const float* __restrict__ enc, const float* __restrict__ alpha,
    const float* __restrict__ adg, const float* __restrict__ b_fbeta,
    unsigned short* __restrict__ x2h, unsigned short* __restrict__ x2l, int t) {
    int b = blockIdx.x;
    int e = blockIdx.y * 256 + threadIdx.x;
    __shared__ float sal[PP];
    if (threadIdx.x < PP) sal[threadIdx.x] = alpha[((size_t)b * TT + t) * PP + threadIdx.x];
    __syncthreads();
    const float* base = enc + (size_t)b * PP * ENCD + e;
    float s = 0.f;
    #pragma unroll 4
    for (int p = 0; p < PP; ++p) s += sal[p] * base[(size_t)p * ENCD];
    float gpre = b_fbeta[e];
    gpre += adg[((size_t)0 * BB + b) * 1024 + AD + e];
    gpre += adg[((size_t)1 * BB + b) * 1024 + AD + e];
    gpre += adg[((size_t)2 * BB + b) * 1024 + AD + e];
    gpre += adg[((size_t)3 * BB + b) * 1024 + AD + e];
    float gate = 1.f / (1.f + __expf(-gpre));
    unsigned short h, l; split2(gate * s, h, l);
    size_t o = ((size_t)(e >> 3) * 64 + b) * 8 + (e & 7);
    x2h[o] = h; x2l[o] = l;
}

// ---- LSTM pointwise; writes c (fp32), next-h split (chunked), and h_all fp32 row ----
__global__ __launch_bounds__(256) void lstm_kernel(
    const float* __restrict__ gp, const float* __restrict__ b_ih,
    const float* __restrict__ b_hh, float* __restrict__ c,
    unsigned short* __restrict__ hc_h, unsigned short* __restrict__ hc_l,
    float* __restrict__ h_all, int t) {
    int b = blockIdx.x; int tid = threadIdx.x;
    #pragma unroll
    for (int jj = 0; jj < 4; ++jj) {
        int j = tid + jj * 256;
        float gi = b_ih[j] + b_hh[j];
        float gf = b_ih[1024 + j] + b_hh[1024 + j];
        float gg = b_ih[2048 + j] + b_hh[2048 + j];
        float go = b_ih[3072 + j] + b_hh[3072 + j];
        #pragma unroll
        for (int ks = 0; ks < 4; ++ks) {
            const float* g = gp + ((size_t)ks * BB + b) * 4096;
            gi += g[j]; gf += g[1024 + j]; gg += g[2048 + j]; go += g[3072 + j];
        }
        float si = 1.f / (1.f + __expf(-gi));
        float sf = 1.f / (1.f + __expf(-gf));
        float so = 1.f / (1.f + __expf(-go));
        float cn = sf * c[b * HD + j] + si * tanhf(gg);
        c[b * HD + j] = cn;
        float hn = so * tanhf(cn);
        unsigned short h, l; split2(hn, h, l);
        size_t o1 = ((size_t)(j >> 3) * 64 + b) * 8 + (j & 7);
        hc_h[o1] = h; hc_l[o1] = l;
        h_all[((size_t)b * TT + t) * HD + j] = hn;
    }
}

extern "C" void kernel_launch(void* const* d_in, const int* in_sizes, int n_in,
                              void* d_out, int out_size, void* d_ws, size_t ws_size,
                              hipStream_t stream) {
    const float* enc      = (const float*)d_in[0];
    const int*   captions = (const int*)d_in[1];
    const float* W_enc    = (const float*)d_in[3];
    const float* b_enc    = (const float*)d_in[4];
    const float* W_dec    = (const float*)d_in[5];
    const float* b_dec    = (const float*)d_in[6];
    const float* W_full   = (const float*)d_in[7];
    const float* table    = (const float*)d_in[9];
    const float* W_ih     = (const float*)d_in[10];   // [1536][4096]
    const float* b_ih     = (const float*)d_in[11];
    const float* W_hh     = (const float*)d_in[12];   // [1024][4096]
    const float* b_hh     = (const float*)d_in[13];
    const float* W_init_h = (const float*)d_in[14];
    const float* b_init_h = (const float*)d_in[15];
    const float* W_init_c = (const float*)d_in[16];
    const float* b_init_c = (const float*)d_in[17];
    const float* W_fbeta  = (const float*)d_in[18];
    const float* b_fbeta  = (const float*)d_in[19];
    const float* W_fc     = (const float*)d_in[20];
    const float* b_fc     = (const float*)d_in[21];

    float* preds  = (float*)d_out;                         // [64][24][20000]
    float* alphas = (float*)d_out + (size_t)BB * TT * VD;  // [64][24][196]

    // ---- workspace carve (alias-aware). Peak ~92 MB. ----
    char* base = (char*)d_ws;
    size_t off = 0;
    auto take = [&](size_t b) { void* r = (void*)(base + off); off += (b + 255) & ~(size_t)255; return r; };
    // Region dead after the 24 steps -> aliased by wfc split (needs 82.4 MB):
    float* att_enc = (float*)take((size_t)12544 * 512 * 4);          // 25.69 MB
    unsigned short* wih_h  = (unsigned short*)take((size_t)192 * 4096 * 8 * 2);  // 12.58
    unsigned short* wih_l  = (unsigned short*)take((size_t)192 * 4096 * 8 * 2);
    unsigned short* whh_h  = (unsigned short*)take((size_t)128 * 4096 * 8 * 2);  // 8.39
    unsigned short* whh_l  = (unsigned short*)take((size_t)128 * 4096 * 8 * 2);
    unsigned short* watt_h = (unsigned short*)take((size_t)128 * 1024 * 8 * 2);  // 2.10
    unsigned short* watt_l = (unsigned short*)take((size_t)128 * 1024 * 8 * 2);
    unsigned short* wenc_h = (unsigned short*)take((size_t)64 * 512 * 8 * 2);    // 0.52
    unsigned short* wenc_l = (unsigned short*)take((size_t)64 * 512 * 8 * 2);
    unsigned short* emb_h  = (unsigned short*)take((size_t)TT * 128 * 64 * 8 * 2); // 3.15
    unsigned short* emb_l  = (unsigned short*)take((size_t)TT * 128 * 64 * 8 * 2);
    float* adg = (float*)take((size_t)4 * BB * 1024 * 4);            // 1.05
    float* gp  = (float*)take((size_t)4 * BB * 4096 * 4);            // 4.19
    size_t alias_end = off;   // ~84.4 MB >= wfc's 82.4 MB
    // wfc aliases [0, alias_end) — written AFTER the steps, read only by final GEMM
    unsigned short* wfc_h = (unsigned short*)(base);
    unsigned short* wfc_l = (unsigned short*)(base + (size_t)128 * VPAD * 8 * 2);
    // Live across phases:
    float* c_buf = (float*)take((size_t)BB * HD * 4);
    float* mf    = (float*)take((size_t)BB * ENCD * 4);
    unsigned short* x2c_h = (unsigned short*)take((size_t)64 * 64 * 8 * 2);
    unsigned short* x2c_l = (unsigned short*)take((size_t)64 * 64 * 8 * 2);
    unsigned short* hc_h  = (unsigned short*)take((size_t)128 * 64 * 8 * 2);
    unsigned short* hc_l  = (unsigned short*)take((size_t)128 * 64 * 8 * 2);
    float* h_all = (float*)take((size_t)TT * BB * HD * 4);           // 6.29 MB

    const int BIG = 1 << 20;

    // ---- one-time conversions (NOT W_fc yet) ----
    split_w_kernel<<<dim3(2, 64), 256, 0, stream>>>(W_enc, wenc_h, wenc_l, 512, 512, 0, 512);
    split_w_kernel<<<dim3(2, 128), 256, 0, stream>>>(W_dec, watt_h, watt_l, 512, 1024, 0, 512);
    split_w_kernel<<<dim3(2, 128), 256, 0, stream>>>(W_fbeta, watt_h, watt_l, 512, 1024, 512, 512);
    split_w_kernel<<<dim3(16, 192), 256, 0, stream>>>(W_ih, wih_h, wih_l, 4096, 4096, 0, 4096);  // 192 chunks = 1536 rows (R2 bug: was 320)
    split_w_kernel<<<dim3(16, 128), 256, 0, stream>>>(W_hh, whh_h, whh_l, 4096, 4096, 0, 4096);
    embed_split_kernel<<<dim3(TT, BB), 128, 0, stream>>>(captions, table, emb_h, emb_l);
    mean_kernel<<<BB, 512, 0, stream>>>(enc, mf);
    init_hc_kernel<<<dim3(BB, 2), 256, 0, stream>>>(mf, W_init_h, b_init_h, W_init_c, b_init_c,
                                                    hc_h, hc_l, c_buf);
    // att_enc = enc @ W_enc + b_enc : M=12544 N=512 K=512 (A fp32 direct)
    mfma_gemm_bigf<<<dim3(4, 98), 256, 0, stream>>>(enc, wenc_h, wenc_l, b_enc, att_enc,
                                                    12544, 512, 512, 512);

    for (int t = 0; t < TT; ++t) {
        // adg = h @ [W_dec | W_fbeta] : M=64 N=1024 K=1024, Ksplit=4
        mfma_gemm_small<<<dim3(8, 4), 256, 0, stream>>>(
            hc_h, hc_l, nullptr, nullptr, nullptr, nullptr, BIG, BIG,
            watt_h, watt_l, nullptr, nullptr, BIG, adg, 1024, 4);
        energy_softmax_kernel<<<BB, 256, 0, stream>>>(att_enc, adg, b_dec, W_full, alphas, t);
        context_x2_kernel<<<dim3(BB, 2), 256, 0, stream>>>(enc, alphas, adg, b_fbeta, x2c_h, x2c_l, t);
        // gates = [emb_t | x2 | h] @ [W_ih ; W_hh] : M=64 N=4096 K=2560, Ksplit=4
        mfma_gemm_small<<<dim3(32, 4), 256, 0, stream>>>(
            emb_h + (size_t)t * 128 * 64 * 8, emb_l + (size_t)t * 128 * 64 * 8,
            x2c_h, x2c_l, hc_h, hc_l, 128, 192,
            wih_h, wih_l, whh_h, whh_l, 192, gp, 4096, 10);
        lstm_kernel<<<BB, 256, 0, stream>>>(gp, b_ih, b_hh, c_buf, hc_h, hc_l, h_all, t);
    }

    // Now the step-phase buffers are dead: split W_fc into the aliased region.
    split_w_kernel<<<dim3(79, 128), 256, 0, stream>>>(W_fc, wfc_h, wfc_l, VD, VPAD, 0, VPAD);
    // preds = h_all @ W_fc + b_fc : M=1536 N=20000 K=1024 (A fp32 direct)
    mfma_gemm_bigf<<<dim3(157, 12), 256, 0, stream>>>(h_all, wfc_h, wfc_l, b_fc, preds,
                                                      TT * BB, VD, VPAD, 1024);
}

// Round 4
// 1834.211 us; speedup vs baseline: 2.0954x; 1.1045x over previous
//
#include <hip/hip_runtime.h>
#include <hip/hip_bf16.h>

// Problem dims (fixed)
#define BB 64      // batch
#define PP 196     // patches
#define ENCD 512   // encoder dim
#define ED 1024    // embed dim
#define HD 1024    // hidden
#define AD 512     // attention dim
#define VD 20000   // vocab
#define TT 24      // timesteps = lengths-1
#define VPAD 20096 // vocab padded to 128
#define NS 8       // K-splits for recurrent GEMMs

typedef __attribute__((ext_vector_type(8))) short short8;
typedef __attribute__((ext_vector_type(4))) short short4v;
typedef __attribute__((ext_vector_type(4))) float f32x4;

// ---- fp32 -> bf16 split (hi + lo), RNE ----
__device__ __forceinline__ unsigned short f2bf(float f) {
    unsigned u = __builtin_bit_cast(unsigned, f);
    u = (u + 0x7FFFu + ((u >> 16) & 1u)) >> 16;
    return (unsigned short)u;
}
__device__ __forceinline__ void split2(float v, unsigned short& h, unsigned short& l) {
    h = f2bf(v);
    float hf = __builtin_bit_cast(float, ((unsigned)h) << 16);
    l = f2bf(v - hf);
}

// ---- weight split: fp32 [K][N] -> chunked bf16 [K/8][Npad][8] hi/lo (zero-pad cols) ----
__global__ __launch_bounds__(256) void split_w_kernel(
    const float* __restrict__ W, unsigned short* __restrict__ oh,
    unsigned short* __restrict__ ol, int N, int Npad, int coff, int Nlaunch) {
    int n = blockIdx.x * 256 + threadIdx.x;
    if (n >= Nlaunch) return;
    int kc = blockIdx.y;
    short8 vh, vl;
    #pragma unroll
    for (int j = 0; j < 8; ++j) {
        float v = (n < N) ? W[(size_t)(kc * 8 + j) * N + n] : 0.f;
        unsigned short h, l; split2(v, h, l);
        vh[j] = (short)h; vl[j] = (short)l;
    }
    size_t o = ((size_t)kc * Npad + coff + n) * 8;
    *(short8*)(oh + o) = vh; *(short8*)(ol + o) = vl;
}

// ---- embedding gather + split -> per-t chunked [128][64][8] ----
__global__ __launch_bounds__(128) void embed_split_kernel(
    const int* __restrict__ captions, const float* __restrict__ table,
    unsigned short* __restrict__ eh, unsigned short* __restrict__ el) {
    int t = blockIdx.x, b = blockIdx.y;
    int kc = threadIdx.x;   // 0..127
    int tok = captions[b * 25 + t];
    const float* row = table + (size_t)tok * ED;
    short8 vh, vl;
    #pragma unroll
    for (int j = 0; j < 8; ++j) {
        unsigned short h, l; split2(row[kc * 8 + j], h, l);
        vh[j] = (short)h; vl[j] = (short)l;
    }
    size_t o = ((size_t)t * 128 * 64 + (size_t)kc * 64 + b) * 8;
    *(short8*)(eh + o) = vh; *(short8*)(el + o) = vl;
}

// ---- mean over patches ----
__global__ __launch_bounds__(512) void mean_kernel(const float* __restrict__ enc,
                                                   float* __restrict__ mf) {
    int b = blockIdx.x; int e = threadIdx.x;
    const float* base = enc + (size_t)b * PP * ENCD + e;
    float s = 0.f;
    #pragma unroll 4
    for (int p = 0; p < PP; ++p) s += base[(size_t)p * ENCD];
    mf[b * ENCD + e] = s * (1.f / PP);
}

// ---- h0/c0 init; h0 goes straight to chunked bf16 split ----
__global__ __launch_bounds__(256) void init_hc_kernel(
    const float* __restrict__ mf,
    const float* __restrict__ Wh, const float* __restrict__ bh,
    const float* __restrict__ Wc, const float* __restrict__ bc,
    unsigned short* __restrict__ hc_h, unsigned short* __restrict__ hc_l,
    float* __restrict__ c0) {
    int b = blockIdx.x;
    int isC = blockIdx.y;
    const float* W    = isC ? Wc : Wh;
    const float* bias = isC ? bc : bh;
    __shared__ float smf[ENCD];
    for (int i = threadIdx.x; i < ENCD; i += 256) smf[i] = mf[b * ENCD + i];
    __syncthreads();
    #pragma unroll
    for (int jj = 0; jj < 4; ++jj) {
        int j = threadIdx.x + jj * 256;
        float acc = bias[j];
        for (int k = 0; k < ENCD; ++k) acc += smf[k] * W[(size_t)k * HD + j];
        if (isC) c0[b * HD + j] = acc;
        else {
            unsigned short h, l; split2(acc, h, l);
            size_t o = ((size_t)(j >> 3) * 64 + b) * 8 + (j & 7);
            hc_h[o] = h; hc_l[o] = l;
        }
    }
}

// ---- big MFMA GEMM, A fp32 [*][K] row-major (in-kernel split), B chunked hi/lo.
//      3-pass. tile 128x128, 4 waves, BK=64. 1-D grid + XCD-bijective swizzle;
//      inner_m=1 -> m-tiles fastest within an XCD chunk (share B panel),
//      inner_m=0 -> n-tiles fastest (share A panel). ----
__global__ __launch_bounds__(256) void mfma_gemm_bigf(
    const float* __restrict__ Ap,
    const unsigned short* __restrict__ Bh, const unsigned short* __restrict__ Bl,
    const float* __restrict__ bias, float* __restrict__ C,
    int N, int Npad, int K, int Mtiles, int Ntiles, int inner_m) {
    __shared__ __align__(16) short lds[32768];   // 64 KB
    short* Ahs = lds;          // [8][128(m^kc)][8]
    short* Als = lds + 8192;
    short* Bhs = lds + 16384;  // [8][128][8]
    short* Bls = lds + 24576;
    int tid = threadIdx.x, lane = tid & 63, w = tid >> 6;
    // XCD-bijective block remap (m204 formula)
    int nwg = Mtiles * Ntiles;
    int orig = blockIdx.x;
    int q = nwg >> 3, r = nwg & 7;
    int xcd = orig & 7;
    int basew = (xcd < r) ? xcd * (q + 1) : r * (q + 1) + (xcd - r) * q;
    int wg = basew + (orig >> 3);
    int mt, nt;
    if (inner_m) { mt = wg % Mtiles; nt = wg / Mtiles; }
    else         { nt = wg % Ntiles; mt = wg / Ntiles; }
    int m0 = mt * 128, n0 = nt * 128;
    int wr = w >> 1, wc = w & 1;
    f32x4 acc[4][4];
    #pragma unroll
    for (int i = 0; i < 4; ++i)
        #pragma unroll
        for (int j = 0; j < 4; ++j) acc[i][j] = (f32x4){0.f, 0.f, 0.f, 0.f};
    int nsteps = K >> 6;
    for (int s = 0; s < nsteps; ++s) {
        int k0 = s * 64, kc0 = s * 8;
        // A fp32 tile 128m x 64k, coalesced along k
        float4 va[8];
        #pragma unroll
        for (int it = 0; it < 8; ++it) {
            int idx = it * 256 + tid; int m = idx >> 4, k4 = idx & 15;
            va[it] = *(const float4*)(Ap + (size_t)(m0 + m) * K + k0 + k4 * 4);
        }
        // B chunked short8 loads
        short8 rb[2][4];
        #pragma unroll
        for (int it = 0; it < 4; ++it) {
            int g = w * 4 + it; int kcl = g >> 1; int rb0 = (g & 1) * 64;
            size_t gb = ((size_t)(kc0 + kcl) * Npad + n0 + rb0 + lane) * 8;
            rb[0][it] = *(const short8*)(Bh + gb);
            rb[1][it] = *(const short8*)(Bl + gb);
        }
        __syncthreads();   // previous iteration's LDS reads complete
        // A: split + swizzled b64 writes
        #pragma unroll
        for (int it = 0; it < 8; ++it) {
            int idx = it * 256 + tid; int m = idx >> 4, k4 = idx & 15;
            int kc = k4 >> 1, jh = (k4 & 1) * 4;
            float vv[4] = {va[it].x, va[it].y, va[it].z, va[it].w};
            short4v hv, lv;
            #pragma unroll
            for (int qq = 0; qq < 4; ++qq) {
                unsigned short h, l; split2(vv[qq], h, l);
                hv[qq] = (short)h; lv[qq] = (short)l;
            }
            int o = kc * 1024 + ((m ^ kc) << 3) + jh;
            *(short4v*)(Ahs + o) = hv;
            *(short4v*)(Als + o) = lv;
        }
        // B: linear b128 writes
        #pragma unroll
        for (int it = 0; it < 4; ++it) {
            int g = w * 4 + it; int kcl = g >> 1; int rb0 = (g & 1) * 64;
            int o = (kcl * 128 + rb0 + lane) * 8;
            *(short8*)(Bhs + o) = rb[0][it];
            *(short8*)(Bls + o) = rb[1][it];
        }
        __syncthreads();
        #pragma unroll
        for (int ks = 0; ks < 2; ++ks) {
            int kq = ks * 4 + (lane >> 4);
            short8 afh[4], afl[4], bfh[4], bfl[4];
            #pragma unroll
            for (int mi = 0; mi < 4; ++mi) {
                int row = wr * 64 + mi * 16 + (lane & 15);
                int o = kq * 1024 + ((row ^ kq) << 3);
                afh[mi] = *(const short8*)(Ahs + o);
                afl[mi] = *(const short8*)(Als + o);
            }
            #pragma unroll
            for (int ni = 0; ni < 4; ++ni) {
                int o = (kq * 128 + wc * 64 + ni * 16 + (lane & 15)) * 8;
                bfh[ni] = *(const short8*)(Bhs + o);
                bfl[ni] = *(const short8*)(Bls + o);
            }
            #pragma unroll
            for (int mi = 0; mi < 4; ++mi)
                #pragma unroll
                for (int ni = 0; ni < 4; ++ni) {
                    acc[mi][ni] = __builtin_amdgcn_mfma_f32_16x16x32_bf16(afh[mi], bfh[ni], acc[mi][ni], 0, 0, 0);
                    acc[mi][ni] = __builtin_amdgcn_mfma_f32_16x16x32_bf16(afh[mi], bfl[ni], acc[mi][ni], 0, 0, 0);
                    acc[mi][ni] = __builtin_amdgcn_mfma_f32_16x16x32_bf16(afl[mi], bfh[ni], acc[mi][ni], 0, 0, 0);
                }
        }
    }
    #pragma unroll
    for (int mi = 0; mi < 4; ++mi) {
        int rrow = m0 + wr * 64 + mi * 16 + ((lane >> 4) << 2);
        #pragma unroll
        for (int ni = 0; ni < 4; ++ni) {
            int c = n0 + wc * 64 + ni * 16 + (lane & 15);
            if (c < N) {
                float bv = bias ? bias[c] : 0.f;
                #pragma unroll
                for (int qq = 0; qq < 4; ++qq)
                    C[(size_t)(rrow + qq) * N + c] = acc[mi][ni][qq] + bv;
            }
        }
    }
}

// ---- small-M MFMA GEMM: M=64, tile 64x128, BK=64, K-split via blockIdx.y ----
// A from up to 3 chunked segments (kc boundaries c0,c1); B from 2 segments (bc0).
// out layout [nsplit][64][Npad], no bias.
__global__ __launch_bounds__(256) void mfma_gemm_small(
    const unsigned short* __restrict__ A0h, const unsigned short* __restrict__ A0l,
    const unsigned short* __restrict__ A1h, const unsigned short* __restrict__ A1l,
    const unsigned short* __restrict__ A2h, const unsigned short* __restrict__ A2l,
    int c0, int c1,
    const unsigned short* __restrict__ B0h, const unsigned short* __restrict__ B0l,
    const unsigned short* __restrict__ B1h, const unsigned short* __restrict__ B1l,
    int bc0, float* __restrict__ out, int Npad, int steps) {
    __shared__ __align__(16) short lds[24576];   // 48 KB
    short* Ahs = lds;          // [8][64][8]
    short* Als = lds + 4096;
    short* Bhs = lds + 8192;   // [8][128][8]
    short* Bls = lds + 16384;
    int tid = threadIdx.x, lane = tid & 63, w = tid >> 6;
    int n0 = blockIdx.x * 128;
    int kc_base = blockIdx.y * steps * 8;
    out += (size_t)blockIdx.y * 64 * Npad;
    f32x4 acc[4][2];
    #pragma unroll
    for (int i = 0; i < 4; ++i)
        #pragma unroll
        for (int j = 0; j < 2; ++j) acc[i][j] = (f32x4){0.f, 0.f, 0.f, 0.f};
    for (int s = 0; s < steps; ++s) {
        int kc0 = kc_base + s * 8;
        short8 raa[2][2], rbb[2][4];
        #pragma unroll
        for (int it = 0; it < 2; ++it) {
            int kcl = w * 2 + it; int kcg = kc0 + kcl;
            const unsigned short *ph, *pl; size_t off;
            if (kcg < c0)       { ph = A0h; pl = A0l; off = ((size_t)kcg * 64 + lane) * 8; }
            else if (kcg < c1)  { ph = A1h; pl = A1l; off = ((size_t)(kcg - c0) * 64 + lane) * 8; }
            else                { ph = A2h; pl = A2l; off = ((size_t)(kcg - c1) * 64 + lane) * 8; }
            raa[0][it] = *(const short8*)(ph + off);
            raa[1][it] = *(const short8*)(pl + off);
        }
        #pragma unroll
        for (int it = 0; it < 4; ++it) {
            int g = w * 4 + it; int kcl = g >> 1; int cb = (g & 1) * 64; int kcg = kc0 + kcl;
            const unsigned short *ph, *pl; size_t off;
            if (kcg < bc0) { ph = B0h; pl = B0l; off = ((size_t)kcg * Npad + n0 + cb + lane) * 8; }
            else           { ph = B1h; pl = B1l; off = ((size_t)(kcg - bc0) * Npad + n0 + cb + lane) * 8; }
            rbb[0][it] = *(const short8*)(ph + off);
            rbb[1][it] = *(const short8*)(pl + off);
        }
        __syncthreads();
        #pragma unroll
        for (int it = 0; it < 2; ++it) {
            int kcl = w * 2 + it; int o = (kcl * 64 + lane) * 8;
            *(short8*)(Ahs + o) = raa[0][it];
            *(short8*)(Als + o) = raa[1][it];
        }
        #pragma unroll
        for (int it = 0; it < 4; ++it) {
            int g = w * 4 + it; int kcl = g >> 1; int cb = (g & 1) * 64;
            int o = (kcl * 128 + cb + lane) * 8;
            *(short8*)(Bhs + o) = rbb[0][it];
            *(short8*)(Bls + o) = rbb[1][it];
        }
        __syncthreads();
        #pragma unroll
        for (int ks = 0; ks < 2; ++ks) {
            int kq = ks * 4 + (lane >> 4);
            short8 afh[4], afl[4], bfh[2], bfl[2];
            #pragma unroll
            for (int mi = 0; mi < 4; ++mi) {
                int o = (kq * 64 + mi * 16 + (lane & 15)) * 8;
                afh[mi] = *(const short8*)(Ahs + o);
                afl[mi] = *(const short8*)(Als + o);
            }
            #pragma unroll
            for (int ni = 0; ni < 2; ++ni) {
                int o = (kq * 128 + w * 32 + ni * 16 + (lane & 15)) * 8;
                bfh[ni] = *(const short8*)(Bhs + o);
                bfl[ni] = *(const short8*)(Bls + o);
            }
            #pragma unroll
            for (int mi = 0; mi < 4; ++mi)
                #pragma unroll
                for (int ni = 0; ni < 2; ++ni) {
                    acc[mi][ni] = __builtin_amdgcn_mfma_f32_16x16x32_bf16(afh[mi], bfh[ni], acc[mi][ni], 0, 0, 0);
                    acc[mi][ni] = __builtin_amdgcn_mfma_f32_16x16x32_bf16(afh[mi], bfl[ni], acc[mi][ni], 0, 0, 0);
                    acc[mi][ni] = __builtin_amdgcn_mfma_f32_16x16x32_bf16(afl[mi], bfh[ni], acc[mi][ni], 0, 0, 0);
                }
        }
        __syncthreads();
    }
    #pragma unroll
    for (int mi = 0; mi < 4; ++mi) {
        int rrow = mi * 16 + ((lane >> 4) << 2);
        #pragma unroll
        for (int ni = 0; ni < 2; ++ni) {
            int c = n0 + w * 32 + ni * 16 + (lane & 15);
            #pragma unroll
            for (int qq = 0; qq < 4; ++qq)
                out[(size_t)(rrow + qq) * Npad + c] = acc[mi][ni][qq];
        }
    }
}

// ---- fused per-step attention: energy + softmax + alpha-out + context + gate -> x2 split ----
__global__ __launch_bounds__(512) void attn_fused_kernel(
    const float* __restrict__ att_enc, const float* __restrict__ adg,
    const float* __restrict__ b_dec, const float* __restrict__ Wfull,
    const float* __restrict__ enc, const float* __restrict__ b_fbeta,
    float* __restrict__ alpha_out, unsigned short* __restrict__ x2h,
    unsigned short* __restrict__ x2l, int t) {
    int b = blockIdx.x; int tid = threadIdx.x;
    __shared__ float sdec[AD], sw[AD], red[512], sal[PP];
    if (tid < AD) {
        float s = b_dec[tid];
        #pragma unroll
        for (int ks = 0; ks < NS; ++ks) s += adg[((size_t)ks * BB + b) * 1024 + tid];
        sdec[tid] = s;
        sw[tid] = Wfull[tid];
    }
    __syncthreads();
    // energy: patch p = tid&255, half = tid>>8 covers a-range [half*256, half*256+256)
    int p = tid & 255, half = tid >> 8;
    float part = 0.f;
    if (p < PP) {
        const float* row = att_enc + ((size_t)b * PP + p) * AD + half * 256;
        const float* sd = sdec + half * 256;
        const float* swp = sw + half * 256;
        #pragma unroll 4
        for (int a0 = 0; a0 < 256; a0 += 4) {
            float4 v = *(const float4*)(row + a0);
            part += fmaxf(v.x + sd[a0 + 0], 0.f) * swp[a0 + 0];
            part += fmaxf(v.y + sd[a0 + 1], 0.f) * swp[a0 + 1];
            part += fmaxf(v.z + sd[a0 + 2], 0.f) * swp[a0 + 2];
            part += fmaxf(v.w + sd[a0 + 3], 0.f) * swp[a0 + 3];
        }
    }
    red[tid] = part;
    __syncthreads();
    float myE = (tid < PP) ? red[tid] + red[tid + 256] : -1e30f;
    __syncthreads();
    red[tid] = myE;
    __syncthreads();
    for (int s = 256; s > 0; s >>= 1) {
        if (tid < s) red[tid] = fmaxf(red[tid], red[tid + s]);
        __syncthreads();
    }
    float mx = red[0];
    __syncthreads();
    float ex = (tid < PP) ? __expf(myE - mx) : 0.f;
    red[tid] = ex;
    __syncthreads();
    for (int s = 256; s > 0; s >>= 1) {
        if (tid < s) red[tid] += red[tid + s];
        __syncthreads();
    }
    float al = ex * (1.f / red[0]);
    if (tid < PP) {
        sal[tid] = al;
        alpha_out[((size_t)b * TT + t) * PP + tid] = al;
    }
    __syncthreads();
    // context + gate for e = tid (512 dims, 1/thread)
    int e = tid;
    const float* basep = enc + (size_t)b * PP * ENCD + e;
    float s = 0.f;
    #pragma unroll 4
    for (int pp = 0; pp < PP; ++pp) s += sal[pp] * basep[(size_t)pp * ENCD];
    float gpre = b_fbeta[e];
    #pragma unroll
    for (int ks = 0; ks < NS; ++ks) gpre += adg[((size_t)ks * BB + b) * 1024 + AD + e];
    float gate = 1.f / (1.f + __expf(-gpre));
    unsigned short h, l; split2(gate * s, h, l);
    size_t o = ((size_t)(e >> 3) * 64 + b) * 8 + (e & 7);
    x2h[o] = h; x2l[o] = l;
}

// ---- LSTM pointwise; writes c (fp32), next-h split (chunked), and h_all fp32 row ----
__global__ __launch_bounds__(256) void lstm_kernel(
    const float* __restrict__ gp, const float* __restrict__ b_ih,
    const float* __restrict__ b_hh, float* __restrict__ c,
    unsigned short* __restrict__ hc_h, unsigned short* __restrict__ hc_l,
    float* __restrict__ h_all, int t) {
    int b = blockIdx.x; int tid = threadIdx.x;
    #pragma unroll
    for (int jj = 0; jj < 4; ++jj) {
        int j = tid + jj * 256;
        float gi = b_ih[j] + b_hh[j];
        float gf = b_ih[1024 + j] + b_hh[1024 + j];
        float gg = b_ih[2048 + j] + b_hh[2048 + j];
        float go = b_ih[3072 + j] + b_hh[3072 + j];
        #pragma unroll
        for (int ks = 0; ks < NS; ++ks) {
            const float* g = gp + ((size_t)ks * BB + b) * 4096;
            gi += g[j]; gf += g[1024 + j]; gg += g[2048 + j]; go += g[3072 + j];
        }
        float si = 1.f / (1.f + __expf(-gi));
        float sf = 1.f / (1.f + __expf(-gf));
        float so = 1.f / (1.f + __expf(-go));
        float cn = sf * c[b * HD + j] + si * tanhf(gg);
        c[b * HD + j] = cn;
        float hn = so * tanhf(cn);
        unsigned short h, l; split2(hn, h, l);
        size_t o1 = ((size_t)(j >> 3) * 64 + b) * 8 + (j & 7);
        hc_h[o1] = h; hc_l[o1] = l;
        h_all[((size_t)b * TT + t) * HD + j] = hn;
    }
}

extern "C" void kernel_launch(void* const* d_in, const int* in_sizes, int n_in,
                              void* d_out, int out_size, void* d_ws, size_t ws_size,
                              hipStream_t stream) {
    const float* enc      = (const float*)d_in[0];
    const int*   captions = (const int*)d_in[1];
    const float* W_enc    = (const float*)d_in[3];
    const float* b_enc    = (const float*)d_in[4];
    const float* W_dec    = (const float*)d_in[5];
    const float* b_dec    = (const float*)d_in[6];
    const float* W_full   = (const float*)d_in[7];
    const float* table    = (const float*)d_in[9];
    const float* W_ih     = (const float*)d_in[10];   // [1536][4096]
    const float* b_ih     = (const float*)d_in[11];
    const float* W_hh     = (const float*)d_in[12];   // [1024][4096]
    const float* b_hh     = (const float*)d_in[13];
    const float* W_init_h = (const float*)d_in[14];
    const float* b_init_h = (const float*)d_in[15];
    const float* W_init_c = (const float*)d_in[16];
    const float* b_init_c = (const float*)d_in[17];
    const float* W_fbeta  = (const float*)d_in[18];
    const float* b_fbeta  = (const float*)d_in[19];
    const float* W_fc     = (const float*)d_in[20];
    const float* b_fc     = (const float*)d_in[21];

    float* preds  = (float*)d_out;                         // [64][24][20000]
    float* alphas = (float*)d_out + (size_t)BB * TT * VD;  // [64][24][196]

    // ---- workspace carve (alias-aware). Peak ~93 MB. ----
    char* base = (char*)d_ws;
    size_t off = 0;
    auto take = [&](size_t b) { void* r = (void*)(base + off); off += (b + 255) & ~(size_t)255; return r; };
    // Region dead after the 24 steps -> aliased by wfc split (needs 82.4 MB):
    float* att_enc = (float*)take((size_t)12544 * 512 * 4);          // 25.69 MB
    unsigned short* wih_h  = (unsigned short*)take((size_t)192 * 4096 * 8 * 2);  // 12.58
    unsigned short* wih_l  = (unsigned short*)take((size_t)192 * 4096 * 8 * 2);
    unsigned short* whh_h  = (unsigned short*)take((size_t)128 * 4096 * 8 * 2);  // 8.39
    unsigned short* whh_l  = (unsigned short*)take((size_t)128 * 4096 * 8 * 2);
    unsigned short* watt_h = (unsigned short*)take((size_t)128 * 1024 * 8 * 2);  // 2.10
    unsigned short* watt_l = (unsigned short*)take((size_t)128 * 1024 * 8 * 2);
    unsigned short* wenc_h = (unsigned short*)take((size_t)64 * 512 * 8 * 2);    // 0.52
    unsigned short* wenc_l = (unsigned short*)take((size_t)64 * 512 * 8 * 2);
    unsigned short* emb_h  = (unsigned short*)take((size_t)TT * 128 * 64 * 8 * 2); // 1.57
    unsigned short* emb_l  = (unsigned short*)take((size_t)TT * 128 * 64 * 8 * 2);
    float* adg = (float*)take((size_t)NS * BB * 1024 * 4);           // 2.10
    float* gp  = (float*)take((size_t)NS * BB * 4096 * 4);           // 8.39
    // wfc aliases [0, off) — written AFTER the steps, read only by final GEMM
    unsigned short* wfc_h = (unsigned short*)(base);
    unsigned short* wfc_l = (unsigned short*)(base + (size_t)128 * VPAD * 8 * 2);
    // Live across phases:
    float* c_buf = (float*)take((size_t)BB * HD * 4);
    float* mf    = (float*)take((size_t)BB * ENCD * 4);
    unsigned short* x2c_h = (unsigned short*)take((size_t)64 * 64 * 8 * 2);
    unsigned short* x2c_l = (unsigned short*)take((size_t)64 * 64 * 8 * 2);
    unsigned short* hc_h  = (unsigned short*)take((size_t)128 * 64 * 8 * 2);
    unsigned short* hc_l  = (unsigned short*)take((size_t)128 * 64 * 8 * 2);
    float* h_all = (float*)take((size_t)TT * BB * HD * 4);           // 6.29 MB

    const int BIG = 1 << 20;

    // ---- one-time conversions (NOT W_fc yet) ----
    split_w_kernel<<<dim3(2, 64), 256, 0, stream>>>(W_enc, wenc_h, wenc_l, 512, 512, 0, 512);
    split_w_kernel<<<dim3(2, 128), 256, 0, stream>>>(W_dec, watt_h, watt_l, 512, 1024, 0, 512);
    split_w_kernel<<<dim3(2, 128), 256, 0, stream>>>(W_fbeta, watt_h, watt_l, 512, 1024, 512, 512);
    split_w_kernel<<<dim3(16, 192), 256, 0, stream>>>(W_ih, wih_h, wih_l, 4096, 4096, 0, 4096);
    split_w_kernel<<<dim3(16, 128), 256, 0, stream>>>(W_hh, whh_h, whh_l, 4096, 4096, 0, 4096);
    embed_split_kernel<<<dim3(TT, BB), 128, 0, stream>>>(captions, table, emb_h, emb_l);
    mean_kernel<<<BB, 512, 0, stream>>>(enc, mf);
    init_hc_kernel<<<dim3(BB, 2), 256, 0, stream>>>(mf, W_init_h, b_init_h, W_init_c, b_init_c,
                                                    hc_h, hc_l, c_buf);
    // att_enc = enc @ W_enc + b_enc : M=12544 N=512 K=512; inner=n (share A panels)
    mfma_gemm_bigf<<<392, 256, 0, stream>>>(enc, wenc_h, wenc_l, b_enc, att_enc,
                                            512, 512, 512, 98, 4, 0);

    for (int t = 0; t < TT; ++t) {
        // adg = h @ [W_dec | W_fbeta] : M=64 N=1024 K=1024, Ksplit=8 (steps=2)
        mfma_gemm_small<<<dim3(8, NS), 256, 0, stream>>>(
            hc_h, hc_l, nullptr, nullptr, nullptr, nullptr, BIG, BIG,
            watt_h, watt_l, nullptr, nullptr, BIG, adg, 1024, 2);
        attn_fused_kernel<<<BB, 512, 0, stream>>>(att_enc, adg, b_dec, W_full, enc, b_fbeta,
                                                  alphas, x2c_h, x2c_l, t);
        // gates = [emb_t | x2 | h] @ [W_ih ; W_hh] : M=64 N=4096 K=2560, Ksplit=8 (steps=5)
        mfma_gemm_small<<<dim3(32, NS), 256, 0, stream>>>(
            emb_h + (size_t)t * 128 * 64 * 8, emb_l + (size_t)t * 128 * 64 * 8,
            x2c_h, x2c_l, hc_h, hc_l, 128, 192,
            wih_h, wih_l, whh_h, whh_l, 192, gp, 4096, 5);
        lstm_kernel<<<BB, 256, 0, stream>>>(gp, b_ih, b_hh, c_buf, hc_h, hc_l, h_all, t);
    }

    // Now the step-phase buffers are dead: split W_fc into the aliased region.
    split_w_kernel<<<dim3(79, 128), 256, 0, stream>>>(W_fc, wfc_h, wfc_l, VD, VPAD, 0, VPAD);
    // preds = h_all @ W_fc + b_fc : M=1536 N=20000 K=1024; inner=m (share B panels)
    mfma_gemm_bigf<<<1884, 256, 0, stream>>>(h_all, wfc_h, wfc_l, b_fc, preds,
                                             VD, VPAD, 1024, 12, 157, 1);
}

// Round 5
// 1513.612 us; speedup vs baseline: 2.5392x; 1.2118x over previous
//
#include <hip/hip_runtime.h>
#include <hip/hip_bf16.h>

// Problem dims (fixed)
#define BB 64      // batch
#define PP 196     // patches
#define ENCD 512   // encoder dim
#define ED 1024    // embed dim
#define HD 1024    // hidden
#define AD 512     // attention dim
#define VD 20000   // vocab
#define TT 24      // timesteps = lengths-1
#define VPAD 20096 // vocab padded to 128
#define NS 8       // K-splits for recurrent GEMMs

typedef __attribute__((ext_vector_type(8))) short short8;
typedef __attribute__((ext_vector_type(4))) short short4v;
typedef __attribute__((ext_vector_type(4))) float f32x4;

// ---- fp32 -> bf16 split (hi + lo), RNE ----
__device__ __forceinline__ unsigned short f2bf(float f) {
    unsigned u = __builtin_bit_cast(unsigned, f);
    u = (u + 0x7FFFu + ((u >> 16) & 1u)) >> 16;
    return (unsigned short)u;
}
__device__ __forceinline__ void split2(float v, unsigned short& h, unsigned short& l) {
    h = f2bf(v);
    float hf = __builtin_bit_cast(float, ((unsigned)h) << 16);
    l = f2bf(v - hf);
}

// ---- weight split: fp32 [K][N] -> chunked bf16 [K/8][Npad][8] hi/lo (zero-pad cols) ----
__global__ __launch_bounds__(256) void split_w_kernel(
    const float* __restrict__ W, unsigned short* __restrict__ oh,
    unsigned short* __restrict__ ol, int N, int Npad, int coff, int Nlaunch) {
    int n = blockIdx.x * 256 + threadIdx.x;
    if (n >= Nlaunch) return;
    int kc = blockIdx.y;
    short8 vh, vl;
    #pragma unroll
    for (int j = 0; j < 8; ++j) {
        float v = (n < N) ? W[(size_t)(kc * 8 + j) * N + n] : 0.f;
        unsigned short h, l; split2(v, h, l);
        vh[j] = (short)h; vl[j] = (short)l;
    }
    size_t o = ((size_t)kc * Npad + coff + n) * 8;
    *(short8*)(oh + o) = vh; *(short8*)(ol + o) = vl;
}

// ---- embedding gather + split -> per-t chunked [128][64][8] ----
__global__ __launch_bounds__(128) void embed_split_kernel(
    const int* __restrict__ captions, const float* __restrict__ table,
    unsigned short* __restrict__ eh, unsigned short* __restrict__ el) {
    int t = blockIdx.x, b = blockIdx.y;
    int kc = threadIdx.x;   // 0..127
    int tok = captions[b * 25 + t];
    const float* row = table + (size_t)tok * ED;
    short8 vh, vl;
    #pragma unroll
    for (int j = 0; j < 8; ++j) {
        unsigned short h, l; split2(row[kc * 8 + j], h, l);
        vh[j] = (short)h; vl[j] = (short)l;
    }
    size_t o = ((size_t)t * 128 * 64 + (size_t)kc * 64 + b) * 8;
    *(short8*)(eh + o) = vh; *(short8*)(el + o) = vl;
}

// ---- mean over patches ----
__global__ __launch_bounds__(512) void mean_kernel(const float* __restrict__ enc,
                                                   float* __restrict__ mf) {
    int b = blockIdx.x; int e = threadIdx.x;
    const float* base = enc + (size_t)b * PP * ENCD + e;
    float s = 0.f;
    #pragma unroll 4
    for (int p = 0; p < PP; ++p) s += base[(size_t)p * ENCD];
    mf[b * ENCD + e] = s * (1.f / PP);
}

// ---- h0/c0 init; h0 goes straight to chunked bf16 split ----
__global__ __launch_bounds__(256) void init_hc_kernel(
    const float* __restrict__ mf,
    const float* __restrict__ Wh, const float* __restrict__ bh,
    const float* __restrict__ Wc, const float* __restrict__ bc,
    unsigned short* __restrict__ hc_h, unsigned short* __restrict__ hc_l,
    float* __restrict__ c0) {
    int b = blockIdx.x;
    int isC = blockIdx.y;
    const float* W    = isC ? Wc : Wh;
    const float* bias = isC ? bc : bh;
    __shared__ float smf[ENCD];
    for (int i = threadIdx.x; i < ENCD; i += 256) smf[i] = mf[b * ENCD + i];
    __syncthreads();
    #pragma unroll
    for (int jj = 0; jj < 4; ++jj) {
        int j = threadIdx.x + jj * 256;
        float acc = bias[j];
        for (int k = 0; k < ENCD; ++k) acc += smf[k] * W[(size_t)k * HD + j];
        if (isC) c0[b * HD + j] = acc;
        else {
            unsigned short h, l; split2(acc, h, l);
            size_t o = ((size_t)(j >> 3) * 64 + b) * 8 + (j & 7);
            hc_h[o] = h; hc_l[o] = l;
        }
    }
}

// ---- big MFMA GEMM, A fp32 [*][K] row-major (in-kernel split), B chunked hi/lo.
//      3-pass. tile 128x128, 4 waves, BK=64. Prefetched: next K-step's global
//      loads issued after the LDS-write barrier, in flight during compute. ----
__global__ __launch_bounds__(256) void mfma_gemm_bigf(
    const float* __restrict__ Ap,
    const unsigned short* __restrict__ Bh, const unsigned short* __restrict__ Bl,
    const float* __restrict__ bias, float* __restrict__ C,
    int N, int Npad, int K, int Mtiles, int Ntiles, int inner_m) {
    __shared__ __align__(16) short lds[32768];   // 64 KB
    short* Ahs = lds;          // [8][128(m^kc)][8]
    short* Als = lds + 8192;
    short* Bhs = lds + 16384;  // [8][128][8]
    short* Bls = lds + 24576;
    int tid = threadIdx.x, lane = tid & 63, w = tid >> 6;
    // XCD-bijective block remap (m204 formula)
    int nwg = Mtiles * Ntiles;
    int orig = blockIdx.x;
    int q = nwg >> 3, r = nwg & 7;
    int xcd = orig & 7;
    int basew = (xcd < r) ? xcd * (q + 1) : r * (q + 1) + (xcd - r) * q;
    int wg = basew + (orig >> 3);
    int mt, nt;
    if (inner_m) { mt = wg % Mtiles; nt = wg / Mtiles; }
    else         { nt = wg % Ntiles; mt = wg / Ntiles; }
    int m0 = mt * 128, n0 = nt * 128;
    int wr = w >> 1, wc = w & 1;
    f32x4 acc[4][4];
    #pragma unroll
    for (int i = 0; i < 4; ++i)
        #pragma unroll
        for (int j = 0; j < 4; ++j) acc[i][j] = (f32x4){0.f, 0.f, 0.f, 0.f};
    int nsteps = K >> 6;
    float4 va[8];
    short8 rb[2][4];
    auto load_step = [&](int s) {
        int k0 = s * 64, kc0 = s * 8;
        #pragma unroll
        for (int it = 0; it < 8; ++it) {
            int idx = it * 256 + tid; int m = idx >> 4, k4 = idx & 15;
            va[it] = *(const float4*)(Ap + (size_t)(m0 + m) * K + k0 + k4 * 4);
        }
        #pragma unroll
        for (int it = 0; it < 4; ++it) {
            int g = w * 4 + it; int kcl = g >> 1; int rb0 = (g & 1) * 64;
            size_t gb = ((size_t)(kc0 + kcl) * Npad + n0 + rb0 + lane) * 8;
            rb[0][it] = *(const short8*)(Bh + gb);
            rb[1][it] = *(const short8*)(Bl + gb);
        }
    };
    load_step(0);
    for (int s = 0; s < nsteps; ++s) {
        __syncthreads();   // previous iteration's LDS reads complete
        // A: split + swizzled b64 writes (waits on va/rb implicitly)
        #pragma unroll
        for (int it = 0; it < 8; ++it) {
            int idx = it * 256 + tid; int m = idx >> 4, k4 = idx & 15;
            int kc = k4 >> 1, jh = (k4 & 1) * 4;
            float vv[4] = {va[it].x, va[it].y, va[it].z, va[it].w};
            short4v hv, lv;
            #pragma unroll
            for (int qq = 0; qq < 4; ++qq) {
                unsigned short h, l; split2(vv[qq], h, l);
                hv[qq] = (short)h; lv[qq] = (short)l;
            }
            int o = kc * 1024 + ((m ^ kc) << 3) + jh;
            *(short4v*)(Ahs + o) = hv;
            *(short4v*)(Als + o) = lv;
        }
        // B: linear b128 writes
        #pragma unroll
        for (int it = 0; it < 4; ++it) {
            int g = w * 4 + it; int kcl = g >> 1; int rb0 = (g & 1) * 64;
            int o = (kcl * 128 + rb0 + lane) * 8;
            *(short8*)(Bhs + o) = rb[0][it];
            *(short8*)(Bls + o) = rb[1][it];
        }
        __syncthreads();
        if (s + 1 < nsteps) load_step(s + 1);   // in flight during compute
        #pragma unroll
        for (int ks = 0; ks < 2; ++ks) {
            int kq = ks * 4 + (lane >> 4);
            short8 afh[4], afl[4], bfh[4], bfl[4];
            #pragma unroll
            for (int mi = 0; mi < 4; ++mi) {
                int row = wr * 64 + mi * 16 + (lane & 15);
                int o = kq * 1024 + ((row ^ kq) << 3);
                afh[mi] = *(const short8*)(Ahs + o);
                afl[mi] = *(const short8*)(Als + o);
            }
            #pragma unroll
            for (int ni = 0; ni < 4; ++ni) {
                int o = (kq * 128 + wc * 64 + ni * 16 + (lane & 15)) * 8;
                bfh[ni] = *(const short8*)(Bhs + o);
                bfl[ni] = *(const short8*)(Bls + o);
            }
            #pragma unroll
            for (int mi = 0; mi < 4; ++mi)
                #pragma unroll
                for (int ni = 0; ni < 4; ++ni) {
                    acc[mi][ni] = __builtin_amdgcn_mfma_f32_16x16x32_bf16(afh[mi], bfh[ni], acc[mi][ni], 0, 0, 0);
                    acc[mi][ni] = __builtin_amdgcn_mfma_f32_16x16x32_bf16(afh[mi], bfl[ni], acc[mi][ni], 0, 0, 0);
                    acc[mi][ni] = __builtin_amdgcn_mfma_f32_16x16x32_bf16(afl[mi], bfh[ni], acc[mi][ni], 0, 0, 0);
                }
        }
    }
    #pragma unroll
    for (int mi = 0; mi < 4; ++mi) {
        int rrow = m0 + wr * 64 + mi * 16 + ((lane >> 4) << 2);
        #pragma unroll
        for (int ni = 0; ni < 4; ++ni) {
            int c = n0 + wc * 64 + ni * 16 + (lane & 15);
            if (c < N) {
                float bv = bias ? bias[c] : 0.f;
                #pragma unroll
                for (int qq = 0; qq < 4; ++qq)
                    C[(size_t)(rrow + qq) * N + c] = acc[mi][ni][qq] + bv;
            }
        }
    }
}

// ---- small-M MFMA GEMM: M=64, tile 64x128, BK=64, K-split via blockIdx.y, prefetched ----
__global__ __launch_bounds__(256) void mfma_gemm_small(
    const unsigned short* __restrict__ A0h, const unsigned short* __restrict__ A0l,
    const unsigned short* __restrict__ A1h, const unsigned short* __restrict__ A1l,
    const unsigned short* __restrict__ A2h, const unsigned short* __restrict__ A2l,
    int c0, int c1,
    const unsigned short* __restrict__ B0h, const unsigned short* __restrict__ B0l,
    const unsigned short* __restrict__ B1h, const unsigned short* __restrict__ B1l,
    int bc0, float* __restrict__ out, int Npad, int steps) {
    __shared__ __align__(16) short lds[24576];   // 48 KB
    short* Ahs = lds;          // [8][64][8]
    short* Als = lds + 4096;
    short* Bhs = lds + 8192;   // [8][128][8]
    short* Bls = lds + 16384;
    int tid = threadIdx.x, lane = tid & 63, w = tid >> 6;
    int n0 = blockIdx.x * 128;
    int kc_base = blockIdx.y * steps * 8;
    out += (size_t)blockIdx.y * 64 * Npad;
    f32x4 acc[4][2];
    #pragma unroll
    for (int i = 0; i < 4; ++i)
        #pragma unroll
        for (int j = 0; j < 2; ++j) acc[i][j] = (f32x4){0.f, 0.f, 0.f, 0.f};
    short8 raa[2][2], rbb[2][4];
    auto load_step = [&](int s) {
        int kc0 = kc_base + s * 8;
        #pragma unroll
        for (int it = 0; it < 2; ++it) {
            int kcl = w * 2 + it; int kcg = kc0 + kcl;
            const unsigned short *ph, *pl; size_t off;
            if (kcg < c0)       { ph = A0h; pl = A0l; off = ((size_t)kcg * 64 + lane) * 8; }
            else if (kcg < c1)  { ph = A1h; pl = A1l; off = ((size_t)(kcg - c0) * 64 + lane) * 8; }
            else                { ph = A2h; pl = A2l; off = ((size_t)(kcg - c1) * 64 + lane) * 8; }
            raa[0][it] = *(const short8*)(ph + off);
            raa[1][it] = *(const short8*)(pl + off);
        }
        #pragma unroll
        for (int it = 0; it < 4; ++it) {
            int g = w * 4 + it; int kcl = g >> 1; int cb = (g & 1) * 64; int kcg = kc0 + kcl;
            const unsigned short *ph, *pl; size_t off;
            if (kcg < bc0) { ph = B0h; pl = B0l; off = ((size_t)kcg * Npad + n0 + cb + lane) * 8; }
            else           { ph = B1h; pl = B1l; off = ((size_t)(kcg - bc0) * Npad + n0 + cb + lane) * 8; }
            rbb[0][it] = *(const short8*)(ph + off);
            rbb[1][it] = *(const short8*)(pl + off);
        }
    };
    load_step(0);
    for (int s = 0; s < steps; ++s) {
        __syncthreads();
        #pragma unroll
        for (int it = 0; it < 2; ++it) {
            int kcl = w * 2 + it; int o = (kcl * 64 + lane) * 8;
            *(short8*)(Ahs + o) = raa[0][it];
            *(short8*)(Als + o) = raa[1][it];
        }
        #pragma unroll
        for (int it = 0; it < 4; ++it) {
            int g = w * 4 + it; int kcl = g >> 1; int cb = (g & 1) * 64;
            int o = (kcl * 128 + cb + lane) * 8;
            *(short8*)(Bhs + o) = rbb[0][it];
            *(short8*)(Bls + o) = rbb[1][it];
        }
        __syncthreads();
        if (s + 1 < steps) load_step(s + 1);
        #pragma unroll
        for (int ks = 0; ks < 2; ++ks) {
            int kq = ks * 4 + (lane >> 4);
            short8 afh[4], afl[4], bfh[2], bfl[2];
            #pragma unroll
            for (int mi = 0; mi < 4; ++mi) {
                int o = (kq * 64 + mi * 16 + (lane & 15)) * 8;
                afh[mi] = *(const short8*)(Ahs + o);
                afl[mi] = *(const short8*)(Als + o);
            }
            #pragma unroll
            for (int ni = 0; ni < 2; ++ni) {
                int o = (kq * 128 + w * 32 + ni * 16 + (lane & 15)) * 8;
                bfh[ni] = *(const short8*)(Bhs + o);
                bfl[ni] = *(const short8*)(Bls + o);
            }
            #pragma unroll
            for (int mi = 0; mi < 4; ++mi)
                #pragma unroll
                for (int ni = 0; ni < 2; ++ni) {
                    acc[mi][ni] = __builtin_amdgcn_mfma_f32_16x16x32_bf16(afh[mi], bfh[ni], acc[mi][ni], 0, 0, 0);
                    acc[mi][ni] = __builtin_amdgcn_mfma_f32_16x16x32_bf16(afh[mi], bfl[ni], acc[mi][ni], 0, 0, 0);
                    acc[mi][ni] = __builtin_amdgcn_mfma_f32_16x16x32_bf16(afl[mi], bfh[ni], acc[mi][ni], 0, 0, 0);
                }
        }
    }
    #pragma unroll
    for (int mi = 0; mi < 4; ++mi) {
        int rrow = mi * 16 + ((lane >> 4) << 2);
        #pragma unroll
        for (int ni = 0; ni < 2; ++ni) {
            int c = n0 + w * 32 + ni * 16 + (lane & 15);
            #pragma unroll
            for (int qq = 0; qq < 4; ++qq)
                out[(size_t)(rrow + qq) * Npad + c] = acc[mi][ni][qq];
        }
    }
}

// ---- per-step: energy + softmax -> alphas (wave-cooperative, 1024 threads) ----
__global__ __launch_bounds__(1024) void energy_softmax_kernel(
    const float* __restrict__ att_enc, const float* __restrict__ adg,
    const float* __restrict__ b_dec, const float* __restrict__ Wfull,
    float* __restrict__ alpha_out, int t) {
    int b = blockIdx.x; int tid = threadIdx.x;
    __shared__ float sdec[AD], sw[AD], sE[256], red[256];
    if (tid < AD) {
        float s = b_dec[tid];
        #pragma unroll
        for (int ks = 0; ks < NS; ++ks) s += adg[((size_t)ks * BB + b) * 1024 + tid];
        sdec[tid] = s;
        sw[tid] = Wfull[tid];
    }
    __syncthreads();
    int w = tid >> 6, lane = tid & 63;
    float4 sd0 = *(const float4*)&sdec[lane * 8];
    float4 sd1 = *(const float4*)&sdec[lane * 8 + 4];
    float4 sw0 = *(const float4*)&sw[lane * 8];
    float4 sw1 = *(const float4*)&sw[lane * 8 + 4];
    for (int p = w; p < PP; p += 16) {
        const float* row = att_enc + ((size_t)b * PP + p) * AD + lane * 8;
        float4 v0 = *(const float4*)row;
        float4 v1 = *(const float4*)(row + 4);
        float part = fmaxf(v0.x + sd0.x, 0.f) * sw0.x + fmaxf(v0.y + sd0.y, 0.f) * sw0.y +
                     fmaxf(v0.z + sd0.z, 0.f) * sw0.z + fmaxf(v0.w + sd0.w, 0.f) * sw0.w +
                     fmaxf(v1.x + sd1.x, 0.f) * sw1.x + fmaxf(v1.y + sd1.y, 0.f) * sw1.y +
                     fmaxf(v1.z + sd1.z, 0.f) * sw1.z + fmaxf(v1.w + sd1.w, 0.f) * sw1.w;
        #pragma unroll
        for (int off = 32; off > 0; off >>= 1) part += __shfl_down(part, off, 64);
        if (lane == 0) sE[p] = part;
    }
    __syncthreads();
    float myE = (tid < PP) ? sE[tid] : -1e30f;
    if (tid < 256) red[tid] = myE;
    __syncthreads();
    for (int s = 128; s > 0; s >>= 1) {
        if (tid < s) red[tid] = fmaxf(red[tid], red[tid + s]);
        __syncthreads();
    }
    float mx = red[0];
    __syncthreads();
    float ex = (tid < PP) ? __expf(myE - mx) : 0.f;
    if (tid < 256) red[tid] = ex;
    __syncthreads();
    for (int s = 128; s > 0; s >>= 1) {
        if (tid < s) red[tid] += red[tid + s];
        __syncthreads();
    }
    if (tid < PP) alpha_out[((size_t)b * TT + t) * PP + tid] = ex * (1.f / red[0]);
}

// ---- per-step: context + gate -> x2 chunked split (4 e-tiles x 128 thr) ----
__global__ __launch_bounds__(128) void context_gate_kernel(
    const float* __restrict__ enc, const float* __restrict__ alpha,
    const float* __restrict__ adg, const float* __restrict__ b_fbeta,
    unsigned short* __restrict__ x2h, unsigned short* __restrict__ x2l, int t) {
    int b = blockIdx.x;
    int e = blockIdx.y * 128 + threadIdx.x;
    __shared__ float sal[PP];
    for (int i = threadIdx.x; i < PP; i += 128)
        sal[i] = alpha[((size_t)b * TT + t) * PP + i];
    __syncthreads();
    const float* basep = enc + (size_t)b * PP * ENCD + e;
    float s = 0.f;
    #pragma unroll 4
    for (int p = 0; p < PP; ++p) s += sal[p] * basep[(size_t)p * ENCD];
    float gpre = b_fbeta[e];
    #pragma unroll
    for (int ks = 0; ks < NS; ++ks) gpre += adg[((size_t)ks * BB + b) * 1024 + AD + e];
    float gate = 1.f / (1.f + __expf(-gpre));
    unsigned short h, l; split2(gate * s, h, l);
    size_t o = ((size_t)(e >> 3) * 64 + b) * 8 + (e & 7);
    x2h[o] = h; x2l[o] = l;
}

// ---- LSTM pointwise; grid (64,4) x 256 thr, 1 j per thread ----
__global__ __launch_bounds__(256) void lstm_kernel(
    const float* __restrict__ gp, const float* __restrict__ b_ih,
    const float* __restrict__ b_hh, float* __restrict__ c,
    unsigned short* __restrict__ hc_h, unsigned short* __restrict__ hc_l,
    float* __restrict__ h_all, int t) {
    int b = blockIdx.x;
    int j = blockIdx.y * 256 + threadIdx.x;
    float gi = b_ih[j] + b_hh[j];
    float gf = b_ih[1024 + j] + b_hh[1024 + j];
    float gg = b_ih[2048 + j] + b_hh[2048 + j];
    float go = b_ih[3072 + j] + b_hh[3072 + j];
    #pragma unroll
    for (int ks = 0; ks < NS; ++ks) {
        const float* g = gp + ((size_t)ks * BB + b) * 4096;
        gi += g[j]; gf += g[1024 + j]; gg += g[2048 + j]; go += g[3072 + j];
    }
    float si = 1.f / (1.f + __expf(-gi));
    float sf = 1.f / (1.f + __expf(-gf));
    float so = 1.f / (1.f + __expf(-go));
    float cn = sf * c[b * HD + j] + si * tanhf(gg);
    c[b * HD + j] = cn;
    float hn = so * tanhf(cn);
    unsigned short h, l; split2(hn, h, l);
    size_t o1 = ((size_t)(j >> 3) * 64 + b) * 8 + (j & 7);
    hc_h[o1] = h; hc_l[o1] = l;
    h_all[((size_t)b * TT + t) * HD + j] = hn;
}

extern "C" void kernel_launch(void* const* d_in, const int* in_sizes, int n_in,
                              void* d_out, int out_size, void* d_ws, size_t ws_size,
                              hipStream_t stream) {
    const float* enc      = (const float*)d_in[0];
    const int*   captions = (const int*)d_in[1];
    const float* W_enc    = (const float*)d_in[3];
    const float* b_enc    = (const float*)d_in[4];
    const float* W_dec    = (const float*)d_in[5];
    const float* b_dec    = (const float*)d_in[6];
    const float* W_full   = (const float*)d_in[7];
    const float* table    = (const float*)d_in[9];
    const float* W_ih     = (const float*)d_in[10];   // [1536][4096]
    const float* b_ih     = (const float*)d_in[11];
    const float* W_hh     = (const float*)d_in[12];   // [1024][4096]
    const float* b_hh     = (const float*)d_in[13];
    const float* W_init_h = (const float*)d_in[14];
    const float* b_init_h = (const float*)d_in[15];
    const float* W_init_c = (const float*)d_in[16];
    const float* b_init_c = (const float*)d_in[17];
    const float* W_fbeta  = (const float*)d_in[18];
    const float* b_fbeta  = (const float*)d_in[19];
    const float* W_fc     = (const float*)d_in[20];
    const float* b_fc     = (const float*)d_in[21];

    float* preds  = (float*)d_out;                         // [64][24][20000]
    float* alphas = (float*)d_out + (size_t)BB * TT * VD;  // [64][24][196]

    // ---- workspace carve (alias-aware). Peak ~93 MB. ----
    char* base = (char*)d_ws;
    size_t off = 0;
    auto take = [&](size_t b) { void* r = (void*)(base + off); off += (b + 255) & ~(size_t)255; return r; };
    // Region dead after the 24 steps -> aliased by wfc split (needs 82.4 MB):
    float* att_enc = (float*)take((size_t)12544 * 512 * 4);          // 25.69 MB
    unsigned short* wih_h  = (unsigned short*)take((size_t)192 * 4096 * 8 * 2);  // 12.58
    unsigned short* wih_l  = (unsigned short*)take((size_t)192 * 4096 * 8 * 2);
    unsigned short* whh_h  = (unsigned short*)take((size_t)128 * 4096 * 8 * 2);  // 8.39
    unsigned short* whh_l  = (unsigned short*)take((size_t)128 * 4096 * 8 * 2);
    unsigned short* watt_h = (unsigned short*)take((size_t)128 * 1024 * 8 * 2);  // 2.10
    unsigned short* watt_l = (unsigned short*)take((size_t)128 * 1024 * 8 * 2);
    unsigned short* wenc_h = (unsigned short*)take((size_t)64 * 512 * 8 * 2);    // 0.52
    unsigned short* wenc_l = (unsigned short*)take((size_t)64 * 512 * 8 * 2);
    unsigned short* emb_h  = (unsigned short*)take((size_t)TT * 128 * 64 * 8 * 2); // 1.57
    unsigned short* emb_l  = (unsigned short*)take((size_t)TT * 128 * 64 * 8 * 2);
    float* adg = (float*)take((size_t)NS * BB * 1024 * 4);           // 2.10
    float* gp  = (float*)take((size_t)NS * BB * 4096 * 4);           // 8.39
    // wfc aliases [0, off) — written AFTER the steps, read only by final GEMM
    unsigned short* wfc_h = (unsigned short*)(base);
    unsigned short* wfc_l = (unsigned short*)(base + (size_t)128 * VPAD * 8 * 2);
    // Live across phases:
    float* c_buf = (float*)take((size_t)BB * HD * 4);
    float* mf    = (float*)take((size_t)BB * ENCD * 4);
    unsigned short* x2c_h = (unsigned short*)take((size_t)64 * 64 * 8 * 2);
    unsigned short* x2c_l = (unsigned short*)take((size_t)64 * 64 * 8 * 2);
    unsigned short* hc_h  = (unsigned short*)take((size_t)128 * 64 * 8 * 2);
    unsigned short* hc_l  = (unsigned short*)take((size_t)128 * 64 * 8 * 2);
    float* h_all = (float*)take((size_t)TT * BB * HD * 4);           // 6.29 MB

    const int BIG = 1 << 20;

    // ---- one-time conversions (NOT W_fc yet) ----
    split_w_kernel<<<dim3(2, 64), 256, 0, stream>>>(W_enc, wenc_h, wenc_l, 512, 512, 0, 512);
    split_w_kernel<<<dim3(2, 128), 256, 0, stream>>>(W_dec, watt_h, watt_l, 512, 1024, 0, 512);
    split_w_kernel<<<dim3(2, 128), 256, 0, stream>>>(W_fbeta, watt_h, watt_l, 512, 1024, 512, 512);
    split_w_kernel<<<dim3(16, 192), 256, 0, stream>>>(W_ih, wih_h, wih_l, 4096, 4096, 0, 4096);
    split_w_kernel<<<dim3(16, 128), 256, 0, stream>>>(W_hh, whh_h, whh_l, 4096, 4096, 0, 4096);
    embed_split_kernel<<<dim3(TT, BB), 128, 0, stream>>>(captions, table, emb_h, emb_l);
    mean_kernel<<<BB, 512, 0, stream>>>(enc, mf);
    init_hc_kernel<<<dim3(BB, 2), 256, 0, stream>>>(mf, W_init_h, b_init_h, W_init_c, b_init_c,
                                                    hc_h, hc_l, c_buf);
    // att_enc = enc @ W_enc + b_enc : M=12544 N=512 K=512; inner=n (share A panels)
    mfma_gemm_bigf<<<392, 256, 0, stream>>>(enc, wenc_h, wenc_l, b_enc, att_enc,
                                            512, 512, 512, 98, 4, 0);

    for (int t = 0; t < TT; ++t) {
        // adg = h @ [W_dec | W_fbeta] : M=64 N=1024 K=1024, Ksplit=8 (steps=2)
        mfma_gemm_small<<<dim3(8, NS), 256, 0, stream>>>(
            hc_h, hc_l, nullptr, nullptr, nullptr, nullptr, BIG, BIG,
            watt_h, watt_l, nullptr, nullptr, BIG, adg, 1024, 2);
        energy_softmax_kernel<<<BB, 1024, 0, stream>>>(att_enc, adg, b_dec, W_full, alphas, t);
        context_gate_kernel<<<dim3(BB, 4), 128, 0, stream>>>(enc, alphas, adg, b_fbeta,
                                                             x2c_h, x2c_l, t);
        // gates = [emb_t | x2 | h] @ [W_ih ; W_hh] : M=64 N=4096 K=2560, Ksplit=8 (steps=5)
        mfma_gemm_small<<<dim3(32, NS), 256, 0, stream>>>(
            emb_h + (size_t)t * 128 * 64 * 8, emb_l + (size_t)t * 128 * 64 * 8,
            x2c_h, x2c_l, hc_h, hc_l, 128, 192,
            wih_h, wih_l, whh_h, whh_l, 192, gp, 4096, 5);
        lstm_kernel<<<dim3(BB, 4), 256, 0, stream>>>(gp, b_ih, b_hh, c_buf, hc_h, hc_l, h_all, t);
    }

    // Now the step-phase buffers are dead: split W_fc into the aliased region.
    split_w_kernel<<<dim3(79, 128), 256, 0, stream>>>(W_fc, wfc_h, wfc_l, VD, VPAD, 0, VPAD);
    // preds = h_all @ W_fc + b_fc : M=1536 N=20000 K=1024; inner=m (share B panels)
    mfma_gemm_bigf<<<1884, 256, 0, stream>>>(h_all, wfc_h, wfc_l, b_fc, preds,
                                             VD, VPAD, 1024, 12, 157, 1);
}